// Round 1
// baseline (2183.513 us; speedup 1.0000x reference)
//
#include <hip/hip_runtime.h>
#include <math.h>

typedef unsigned short u16;
typedef __bf16 bf16x8 __attribute__((ext_vector_type(8)));
typedef float f32x4 __attribute__((ext_vector_type(4)));

#define L_   12
#define NTOK 3136
#define MP   3200

__device__ __forceinline__ float b2f(u16 v){ return __builtin_bit_cast(float, (unsigned)v<<16); }
__device__ __forceinline__ u16 f2b(float f){
    unsigned u = __builtin_bit_cast(unsigned, f);
    u += 0x7fffu + ((u>>16)&1u);
    return (u16)(u>>16);
}
__device__ __forceinline__ float wsum(float v){
    #pragma unroll
    for (int o=32;o;o>>=1) v += __shfl_xor(v,o);
    return v;
}

// ---------------- weight transpose + fp32->bf16 convert -------------------
// src: (R,C) f32 row-major, batched along z; dst: (C,R) bf16 row-major
__global__ __launch_bounds__(256) void k_transpose(const float* __restrict__ src,
                                                   u16* __restrict__ dst, int R, int C){
    __shared__ float t[32][33];
    long long base = (long long)blockIdx.z * R * C;
    int c0 = blockIdx.x<<5, r0 = blockIdx.y<<5;
    int tx = threadIdx.x & 31, ty = threadIdx.x >> 5;
    #pragma unroll
    for (int i=0;i<32;i+=8)
        t[ty+i][tx] = src[base + (long long)(r0+ty+i)*C + c0 + tx];
    __syncthreads();
    #pragma unroll
    for (int i=0;i<32;i+=8)
        dst[base + (long long)(c0+ty+i)*R + r0 + tx] = f2b(t[tx][ty+i]);
}

// ---------------- patch extraction ---------------------------------------
__global__ __launch_bounds__(256) void k_patches(const float* __restrict__ x, u16* __restrict__ out){
    int idx = blockIdx.x*256 + threadIdx.x;
    int row = idx / 768, col = idx - row*768;
    float v = 0.f;
    if (row < NTOK){
        int b = row / 196, t = row - b*196;
        int gi = t / 14, gj = t - gi*14;
        int c = col >> 8, rem = col & 255, pi = rem >> 4, pj = rem & 15;
        v = x[((long long)(b*3 + c)*224 + gi*16 + pi)*224 + gj*16 + pj];
    }
    out[idx] = f2b(v);
}

// ---------------- GEMM: C = A(M,K)bf16 @ B(K,N)bf16 + bias ----------------
// B supplied TRANSPOSED: Bt is (N,K) bf16 row-major.
// EPI: 0 = bf16 out, 1 = bf16 out + exact GELU, 2 = f32 out, 3 = f32 accumulate
template<int EPI>
__global__ __launch_bounds__(256) void gemm_tn(
    const u16* __restrict__ A, int lda, int aOffStride,
    const u16* __restrict__ Bt, long long btStride,
    const float* __restrict__ bias, int biasStride,
    void* __restrict__ Cbase, int ldc, int colOffStride,
    int K)
{
    int z = blockIdx.z;
    const u16* Az   = A  + (long long)z*aOffStride;
    const u16* Btz  = Bt + (long long)z*btStride;
    const float* biasz = bias + (long long)z*biasStride;
    int colOff = z*colOffStride;
    int m0 = blockIdx.y*128, n0 = blockIdx.x*128;

    __shared__ u16 As[128*64];
    __shared__ u16 Bs[128*64];

    int tid = threadIdx.x;
    int lane = tid & 63;
    int wave = tid >> 6;
    int wm = wave >> 1, wn = wave & 1;

    f32x4 acc[4][4];
    #pragma unroll
    for (int m=0;m<4;m++)
        #pragma unroll
        for (int n=0;n<4;n++) acc[m][n] = (f32x4){0.f,0.f,0.f,0.f};

    int sr = tid >> 3;      // 0..31 (row within 32-row slab)
    int sc = tid & 7;       // 16B chunk within 128B row

    int nkt = K >> 6;
    for (int kt=0; kt<nkt; ++kt){
        __syncthreads();
        #pragma unroll
        for (int it=0; it<4; ++it){
            int r = sr + it*32;
            int bo = (sc*16) ^ ((r&7)<<4);
            uint4 va = *reinterpret_cast<const uint4*>(Az  + (long long)(m0+r)*lda + (kt<<6) + sc*8);
            *reinterpret_cast<uint4*>((char*)As + r*128 + bo) = va;
            uint4 vb = *reinterpret_cast<const uint4*>(Btz + (long long)(n0+r)*K  + (kt<<6) + sc*8);
            *reinterpret_cast<uint4*>((char*)Bs + r*128 + bo) = vb;
        }
        __syncthreads();
        #pragma unroll
        for (int kk=0; kk<2; ++kk){
            bf16x8 af[4], bfr[4];
            int kb = (kk*32 + ((lane>>4)<<3))*2;  // byte offset of 8-elem k chunk
            #pragma unroll
            for (int m=0;m<4;m++){
                int r = wm*64 + m*16 + (lane&15);
                af[m] = *reinterpret_cast<const bf16x8*>((const char*)As + r*128 + (kb ^ ((r&7)<<4)));
            }
            #pragma unroll
            for (int n=0;n<4;n++){
                int r = wn*64 + n*16 + (lane&15);
                bfr[n] = *reinterpret_cast<const bf16x8*>((const char*)Bs + r*128 + (kb ^ ((r&7)<<4)));
            }
            #pragma unroll
            for (int m=0;m<4;m++)
                #pragma unroll
                for (int n=0;n<4;n++)
                    acc[m][n] = __builtin_amdgcn_mfma_f32_16x16x32_bf16(af[m], bfr[n], acc[m][n], 0,0,0);
        }
    }

    int rbase = m0 + wm*64;
    int nbase = n0 + wn*64;
    #pragma unroll
    for (int m=0;m<4;m++){
        #pragma unroll
        for (int n=0;n<4;n++){
            int ncol = nbase + n*16 + (lane&15);
            float bv = biasz[ncol];
            long long cix = (long long)(ncol + colOff);
            #pragma unroll
            for (int r4=0;r4<4;r4++){
                int row = rbase + m*16 + ((lane>>4)<<2) + r4;
                float v = acc[m][n][r4] + bv;
                long long idx = (long long)row*ldc + cix;
                if (EPI==0)      ((u16*)Cbase)[idx] = f2b(v);
                else if (EPI==1){
                    float gl = 0.5f*v*(1.f + erff(v*0.70710678118f));
                    ((u16*)Cbase)[idx] = f2b(gl);
                }
                else if (EPI==2) ((float*)Cbase)[idx] = v;
                else             ((float*)Cbase)[idx] += v;
            }
        }
    }
}

// ---------------- LayerNorm (width 384), f32 in, bf16 out -----------------
__global__ __launch_bounds__(256) void k_ln_bf16(const float* __restrict__ in,
        const float* __restrict__ g, const float* __restrict__ b, u16* __restrict__ out){
    int row = blockIdx.x*4 + (threadIdx.x>>6);
    int lane = threadIdx.x & 63;
    const float* rp = in + (long long)row*384;
    float v[6]; float s = 0.f;
    #pragma unroll
    for (int i=0;i<6;i++){ v[i] = rp[lane + i*64]; s += v[i]; }
    float mu = wsum(s)*(1.f/384.f);
    float q = 0.f;
    #pragma unroll
    for (int i=0;i<6;i++){ float d = v[i]-mu; q += d*d; }
    float rs = rsqrtf(wsum(q)*(1.f/384.f) + 1e-5f);
    u16* op = out + (long long)row*384;
    #pragma unroll
    for (int i=0;i<6;i++){ int c = lane + i*64; op[c] = f2b((v[i]-mu)*rs*g[c] + b[c]); }
}

// patch-embed LN + positional add -> h (f32)
__global__ __launch_bounds__(256) void k_pe_ln(const float* __restrict__ in,
        const float* __restrict__ g, const float* __restrict__ b,
        const float* __restrict__ pos, float* __restrict__ h){
    int row = blockIdx.x*4 + (threadIdx.x>>6);
    int lane = threadIdx.x & 63;
    const float* rp = in + (long long)row*384;
    float v[6]; float s = 0.f;
    #pragma unroll
    for (int i=0;i<6;i++){ v[i] = rp[lane + i*64]; s += v[i]; }
    float mu = wsum(s)*(1.f/384.f);
    float q = 0.f;
    #pragma unroll
    for (int i=0;i<6;i++){ float d = v[i]-mu; q += d*d; }
    float rs = rsqrtf(wsum(q)*(1.f/384.f) + 1e-5f);
    int t = row % 196;
    const float* pp = pos + (long long)t*384;
    float* op = h + (long long)row*384;
    #pragma unroll
    for (int i=0;i<6;i++){ int c = lane + i*64; op[c] = (v[i]-mu)*rs*g[c] + b[c] + pp[c]; }
}

// merged -> LN(sn) -> h += ; then hn2 = LN(h, n2) bf16
__global__ __launch_bounds__(256) void k_sn_ln(const float* __restrict__ merged,
        const float* __restrict__ sg, const float* __restrict__ sb,
        float* __restrict__ h,
        const float* __restrict__ n2g, const float* __restrict__ n2b,
        u16* __restrict__ hn2){
    int row = blockIdx.x*4 + (threadIdx.x>>6);
    int lane = threadIdx.x & 63;
    const float* rp = merged + (long long)row*384;
    float v[6]; float s = 0.f;
    #pragma unroll
    for (int i=0;i<6;i++){ v[i] = rp[lane + i*64]; s += v[i]; }
    float mu = wsum(s)*(1.f/384.f);
    float q = 0.f;
    #pragma unroll
    for (int i=0;i<6;i++){ float d = v[i]-mu; q += d*d; }
    float rs = rsqrtf(wsum(q)*(1.f/384.f) + 1e-5f);
    float* hp = h + (long long)row*384;
    float hv[6]; float s2 = 0.f;
    #pragma unroll
    for (int i=0;i<6;i++){
        int c = lane + i*64;
        float nv = hp[c] + (v[i]-mu)*rs*sg[c] + sb[c];
        hp[c] = nv; hv[i] = nv; s2 += nv;
    }
    float mu2 = wsum(s2)*(1.f/384.f);
    float q2 = 0.f;
    #pragma unroll
    for (int i=0;i<6;i++){ float d = hv[i]-mu2; q2 += d*d; }
    float rs2 = rsqrtf(wsum(q2)*(1.f/384.f) + 1e-5f);
    u16* op = hn2 + (long long)row*384;
    #pragma unroll
    for (int i=0;i<6;i++){ int c = lane + i*64; op[c] = f2b((hv[i]-mu2)*rs2*n2g[c] + n2b[c]); }
}

// final LN -> f32 out (valid rows only)
__global__ __launch_bounds__(256) void k_fin(const float* __restrict__ h,
        const float* __restrict__ g, const float* __restrict__ b, float* __restrict__ out){
    int row = blockIdx.x*4 + (threadIdx.x>>6);
    int lane = threadIdx.x & 63;
    const float* rp = h + (long long)row*384;
    float v[6]; float s = 0.f;
    #pragma unroll
    for (int i=0;i<6;i++){ v[i] = rp[lane + i*64]; s += v[i]; }
    float mu = wsum(s)*(1.f/384.f);
    float q = 0.f;
    #pragma unroll
    for (int i=0;i<6;i++){ float d = v[i]-mu; q += d*d; }
    float rs = rsqrtf(wsum(q)*(1.f/384.f) + 1e-5f);
    float* op = out + (long long)row*384;
    #pragma unroll
    for (int i=0;i<6;i++){ int c = lane + i*64; op[c] = (v[i]-mu)*rs*g[c] + b[c]; }
}

// gated SiLU*sigmoid + per-768 LN : zg(MP,6144)bf16 -> lnz(MP,3072)bf16
__global__ __launch_bounds__(256) void k_gate_ln(const u16* __restrict__ zg,
        const float* __restrict__ lag, const float* __restrict__ lab, u16* __restrict__ lnz){
    int unit = blockIdx.x*4 + (threadIdx.x>>6);
    int lane = threadIdx.x & 63;
    int row = unit >> 2, dir = unit & 3;
    const u16* zp = zg + (long long)row*6144 + dir*1536;
    float gated[12]; float s = 0.f;
    #pragma unroll
    for (int p=0;p<3;p++){
        int j = p*256 + lane*4;
        ushort4 zv = *reinterpret_cast<const ushort4*>(zp + j);
        ushort4 gv = *reinterpret_cast<const ushort4*>(zp + 768 + j);
        const u16* za = (const u16*)&zv;
        const u16* ga = (const u16*)&gv;
        #pragma unroll
        for (int qq=0;qq<4;qq++){
            float zf = b2f(za[qq]);
            float gf = b2f(ga[qq]);
            float val = zf/(1.f+__expf(-zf)) * (1.f/(1.f+__expf(-gf)));
            gated[p*4+qq] = val; s += val;
        }
    }
    float mu = wsum(s)*(1.f/768.f);
    float q = 0.f;
    #pragma unroll
    for (int i=0;i<12;i++){ float d = gated[i]-mu; q += d*d; }
    float rs = rsqrtf(wsum(q)*(1.f/768.f) + 1e-5f);
    const float* gg = lag + dir*768;
    const float* bb = lab + dir*768;
    u16* op = lnz + (long long)row*3072 + dir*768;
    #pragma unroll
    for (int p=0;p<3;p++){
        int j = p*256 + lane*4;
        ushort4 ov;
        u16* oa = (u16*)&ov;
        #pragma unroll
        for (int qq=0;qq<4;qq++)
            oa[qq] = f2b((gated[p*4+qq]-mu)*rs*gg[j+qq] + bb[j+qq]);
        *reinterpret_cast<ushort4*>(op + j) = ov;
    }
}

// --------------------------------------------------------------------------
extern "C" void kernel_launch(void* const* d_in, const int* in_sizes, int n_in,
                              void* d_out, int out_size, void* d_ws, size_t ws_size,
                              hipStream_t stream)
{
    const float* x      = (const float*)d_in[0];
    const float* patch_w= (const float*)d_in[1];
    const float* patch_b= (const float*)d_in[2];
    const float* pe_g   = (const float*)d_in[3];
    const float* pe_b   = (const float*)d_in[4];
    const float* pos    = (const float*)d_in[5];
    const float* n1_g   = (const float*)d_in[6];
    const float* n1_b   = (const float*)d_in[7];
    const float* pi_w   = (const float*)d_in[8];
    const float* pi_b   = (const float*)d_in[9];
    const float* po_w   = (const float*)d_in[10];
    const float* po_b   = (const float*)d_in[11];
    const float* la_g   = (const float*)d_in[12];
    const float* la_b   = (const float*)d_in[13];
    const float* mg_w   = (const float*)d_in[14];
    const float* mg_b   = (const float*)d_in[15];
    const float* sn_g   = (const float*)d_in[16];
    const float* sn_b   = (const float*)d_in[17];
    const float* n2_g   = (const float*)d_in[18];
    const float* n2_b   = (const float*)d_in[19];
    const float* m1_w   = (const float*)d_in[20];
    const float* m1_b   = (const float*)d_in[21];
    const float* m2_w   = (const float*)d_in[22];
    const float* m2_b   = (const float*)d_in[23];
    const float* fin_g  = (const float*)d_in[24];
    const float* fin_b  = (const float*)d_in[25];

    char* wptr = (char*)d_ws;
    auto carve = [&](long long elems, int esz)->void*{
        void* p = (void*)wptr;
        wptr += ((elems*(long long)esz + 255)/256)*256;
        return p;
    };

    u16* wt_pi = (u16*)carve(28311552, 2);   // (12*4) x (1536,384)
    u16* wt_po = (u16*)carve(14155776, 2);   // (12*4) x (384,768)
    u16* wt_mg = (u16*)carve(7077888, 2);    // 12 x (384,1536)
    u16* wt_m1 = (u16*)carve(7077888, 2);    // 12 x (1536,384)
    u16* wt_m2 = (u16*)carve(7077888, 2);    // 12 x (384,1536)
    u16* wt_pe = (u16*)carve(294912, 2);     // (384,768)
    float* h      = (float*)carve((long long)MP*384, 4);
    float* merged = (float*)carve((long long)MP*384, 4);
    u16* patches  = (u16*)carve((long long)MP*768, 2);
    u16* hn       = (u16*)carve((long long)MP*384, 2);
    u16* zg       = (u16*)carve((long long)MP*6144, 2);
    u16* lnz      = (u16*)carve((long long)MP*3072, 2);
    u16* outs     = (u16*)carve((long long)MP*1536, 2);

    dim3 blk(256);

    // weight transposes (fp32 -> bf16, B^T layout)
    k_transpose<<<dim3(48,12,48), blk, 0, stream>>>(pi_w,   wt_pi, 384, 1536);
    k_transpose<<<dim3(12,24,48), blk, 0, stream>>>(po_w,   wt_po, 768, 384);
    k_transpose<<<dim3(12,48,12), blk, 0, stream>>>(mg_w,   wt_mg, 1536, 384);
    k_transpose<<<dim3(48,12,12), blk, 0, stream>>>(m1_w,   wt_m1, 384, 1536);
    k_transpose<<<dim3(12,48,12), blk, 0, stream>>>(m2_w,   wt_m2, 1536, 384);
    k_transpose<<<dim3(12,24,1),  blk, 0, stream>>>(patch_w,wt_pe, 768, 384);

    // patch embed
    k_patches<<<dim3(MP*768/256), blk, 0, stream>>>(x, patches);
    gemm_tn<2><<<dim3(3,25,1), blk, 0, stream>>>(patches, 768, 0, wt_pe, 0, patch_b, 0,
                                                 merged, 384, 0, 768);
    k_pe_ln<<<dim3(MP/4), blk, 0, stream>>>(merged, pe_g, pe_b, pos, h);

    for (int l=0; l<L_; ++l){
        k_ln_bf16<<<dim3(MP/4), blk, 0, stream>>>(h, n1_g + l*384, n1_b + l*384, hn);
        // 4 direction input projections: hn(MP,384) @ pi_w[l,i] -> zg cols i*1536..
        gemm_tn<0><<<dim3(12,25,4), blk, 0, stream>>>(hn, 384, 0,
            wt_pi + (long long)l*4*589824, 589824,
            pi_b + (long long)l*4*1536, 1536,
            zg, 6144, 1536, 384);
        k_gate_ln<<<dim3(MP), blk, 0, stream>>>(zg, la_g + (long long)l*4*768, la_b + (long long)l*4*768, lnz);
        // 4 output projections: lnz[:, i*768:] @ po_w[l,i] -> outs cols i*384..
        gemm_tn<0><<<dim3(3,25,4), blk, 0, stream>>>(lnz, 3072, 768,
            wt_po + (long long)l*4*294912, 294912,
            po_b + (long long)l*4*384, 384,
            outs, 1536, 384, 768);
        // merge: outs(MP,1536) @ mg_w[l] -> merged(MP,384) f32
        gemm_tn<2><<<dim3(3,25,1), blk, 0, stream>>>(outs, 1536, 0,
            wt_mg + (long long)l*589824, 0,
            mg_b + (long long)l*384, 0,
            merged, 384, 0, 1536);
        k_sn_ln<<<dim3(MP/4), blk, 0, stream>>>(merged, sn_g + l*384, sn_b + l*384,
                                                h, n2_g + l*384, n2_b + l*384, hn);
        // MLP
        gemm_tn<1><<<dim3(12,25,1), blk, 0, stream>>>(hn, 384, 0,
            wt_m1 + (long long)l*589824, 0,
            m1_b + (long long)l*1536, 0,
            outs, 1536, 0, 384);
        gemm_tn<3><<<dim3(3,25,1), blk, 0, stream>>>(outs, 1536, 0,
            wt_m2 + (long long)l*589824, 0,
            m2_b + (long long)l*384, 0,
            h, 384, 0, 1536);
    }

    k_fin<<<dim3(NTOK/4), blk, 0, stream>>>(h, fin_g, fin_b, (float*)d_out);
}

// Round 2
// 1987.444 us; speedup vs baseline: 1.0987x; 1.0987x over previous
//
#include <hip/hip_runtime.h>
#include <math.h>

typedef unsigned short u16;
typedef __bf16 bf16x8 __attribute__((ext_vector_type(8)));
typedef float f32x4 __attribute__((ext_vector_type(4)));

#define L_   12
#define NTOK 3136
#define MP   3200

__device__ __forceinline__ float b2f(u16 v){ return __builtin_bit_cast(float, (unsigned)v<<16); }
__device__ __forceinline__ u16 f2b(float f){
    unsigned u = __builtin_bit_cast(unsigned, f);
    u += 0x7fffu + ((u>>16)&1u);
    return (u16)(u>>16);
}
__device__ __forceinline__ float wsum(float v){
    #pragma unroll
    for (int o=32;o;o>>=1) v += __shfl_xor(v,o);
    return v;
}
__device__ __forceinline__ void gl_lds16(const void* g, void* l){
    __builtin_amdgcn_global_load_lds(
        (const __attribute__((address_space(1))) void*)g,
        (__attribute__((address_space(3))) void*)l, 16, 0, 0);
}

// ---------------- weight transpose + fp32->bf16 convert -------------------
__global__ __launch_bounds__(256) void k_transpose(const float* __restrict__ src,
                                                   u16* __restrict__ dst, int R, int C){
    __shared__ float t[32][33];
    long long base = (long long)blockIdx.z * R * C;
    int c0 = blockIdx.x<<5, r0 = blockIdx.y<<5;
    int tx = threadIdx.x & 31, ty = threadIdx.x >> 5;
    #pragma unroll
    for (int i=0;i<32;i+=8)
        t[ty+i][tx] = src[base + (long long)(r0+ty+i)*C + c0 + tx];
    __syncthreads();
    #pragma unroll
    for (int i=0;i<32;i+=8)
        dst[base + (long long)(c0+ty+i)*R + r0 + tx] = f2b(t[tx][ty+i]);
}

// ---------------- patch extraction ---------------------------------------
__global__ __launch_bounds__(256) void k_patches(const float* __restrict__ x, u16* __restrict__ out){
    int idx = blockIdx.x*256 + threadIdx.x;
    int row = idx / 768, col = idx - row*768;
    float v = 0.f;
    if (row < NTOK){
        int b = row / 196, t = row - b*196;
        int gi = t / 14, gj = t - gi*14;
        int c = col >> 8, rem = col & 255, pi = rem >> 4, pj = rem & 15;
        v = x[((long long)(b*3 + c)*224 + gi*16 + pi)*224 + gj*16 + pj];
    }
    out[idx] = f2b(v);
}

// ---------------- GEMM: C = A(M,K)bf16 @ Bt(N,K)bf16 + bias ---------------
// EPI: 0 = bf16 out, 1 = bf16 out + exact GELU, 2 = f32 out
// Split-K: kOffPerZ != 0 -> z = split index (bias only at z==0), C offset via colOffStride.
template<int EPI>
__global__ __launch_bounds__(256) void gemm_tn(
    const u16* __restrict__ A, int lda, long long aOffStride,
    const u16* __restrict__ Bt, long long btStride, int ldb,
    int kOffPerZ,
    const float* __restrict__ bias, int biasStride,
    void* __restrict__ Cbase, int ldc, int colOffStride,
    int K)
{
    int z = blockIdx.z;
    const u16* Az  = A  + (long long)z*aOffStride + (long long)z*kOffPerZ;
    const u16* Btz = Bt + (long long)z*btStride  + (long long)z*kOffPerZ;
    const float* biasz = bias + (long long)z*biasStride;
    bool addb = (kOffPerZ == 0) || (z == 0);
    int colOff = z*colOffStride;
    int m0 = blockIdx.y*128, n0 = blockIdx.x*128;

    __shared__ u16 As[128*64];
    __shared__ u16 Bs[128*64];

    int tid = threadIdx.x;
    int lane = tid & 63;
    int w = tid >> 6;
    int wm = w >> 1, wn = w & 1;
    int rsub = lane >> 3, csub = lane & 7;

    // per-lane global row pointers for staging (4 issues each for A and B)
    const u16* ga[4]; const u16* gb[4];
    #pragma unroll
    for (int j=0;j<4;j++){
        int r = w*32 + j*8 + rsub;
        ga[j] = Az  + (long long)(m0 + r)*lda + csub*8;
        gb[j] = Btz + (long long)(n0 + r)*ldb + csub*8;
    }
    u16* la[4]; u16* lb[4];
    #pragma unroll
    for (int j=0;j<4;j++){
        la[j] = As + (w*32 + j*8)*64;
        lb[j] = Bs + (w*32 + j*8)*64;
    }

    f32x4 acc[4][4];
    #pragma unroll
    for (int m=0;m<4;m++)
        #pragma unroll
        for (int n=0;n<4;n++) acc[m][n] = (f32x4){0.f,0.f,0.f,0.f};

    int nkt = K >> 6;
    for (int kt=0; kt<nkt; ++kt){
        int ko = kt*64;
        #pragma unroll
        for (int j=0;j<4;j++){
            gl_lds16(ga[j] + ko, la[j]);
            gl_lds16(gb[j] + ko, lb[j]);
        }
        __syncthreads();   // drains vmcnt -> staged data visible
        #pragma unroll
        for (int kk=0; kk<2; ++kk){
            bf16x8 af[4], bfr[4];
            int kb = (kk*32 + ((lane>>4)<<3))*2;  // byte offset of 8-elem k chunk
            #pragma unroll
            for (int m=0;m<4;m++){
                int r = wm*64 + m*16 + (lane&15);
                af[m] = *reinterpret_cast<const bf16x8*>((const char*)As + r*128 + kb);
            }
            #pragma unroll
            for (int n=0;n<4;n++){
                int r = wn*64 + n*16 + (lane&15);
                bfr[n] = *reinterpret_cast<const bf16x8*>((const char*)Bs + r*128 + kb);
            }
            #pragma unroll
            for (int m=0;m<4;m++)
                #pragma unroll
                for (int n=0;n<4;n++)
                    acc[m][n] = __builtin_amdgcn_mfma_f32_16x16x32_bf16(af[m], bfr[n], acc[m][n], 0,0,0);
        }
        __syncthreads();   // all waves done reading before next stage
    }

    int rbase = m0 + wm*64;
    int nbase = n0 + wn*64;
    #pragma unroll
    for (int m=0;m<4;m++){
        #pragma unroll
        for (int n=0;n<4;n++){
            int ncol = nbase + n*16 + (lane&15);
            float bv = addb ? biasz[ncol] : 0.f;
            long long cix = (long long)(ncol + colOff);
            #pragma unroll
            for (int r4=0;r4<4;r4++){
                int row = rbase + m*16 + ((lane>>4)<<2) + r4;
                float v = acc[m][n][r4] + bv;
                long long idx = (long long)row*ldc + cix;
                if (EPI==0)      ((u16*)Cbase)[idx] = f2b(v);
                else if (EPI==1){
                    float gl = 0.5f*v*(1.f + erff(v*0.70710678118f));
                    ((u16*)Cbase)[idx] = f2b(gl);
                }
                else             ((float*)Cbase)[idx] = v;
            }
        }
    }
}

// -------- h += sum(parts); LN -> out. MODE 0: bf16 hn + update h. MODE 1: f32 out.
template<int MODE>
__global__ __launch_bounds__(256) void k_addln(float* __restrict__ h,
        const float* __restrict__ parts, int np,
        const float* __restrict__ g, const float* __restrict__ b, void* __restrict__ out){
    int row = blockIdx.x*4 + (threadIdx.x>>6);
    int lane = threadIdx.x & 63;
    float* hp = h + (long long)row*384;
    float v[6]; float s = 0.f;
    #pragma unroll
    for (int i=0;i<6;i++){
        int c = lane + i*64;
        float t = hp[c];
        for (int p=0;p<np;p++) t += parts[(long long)p*MP*384 + (long long)row*384 + c];
        v[i] = t; s += t;
    }
    if (MODE==0 && np){
        #pragma unroll
        for (int i=0;i<6;i++) hp[lane + i*64] = v[i];
    }
    float mu = wsum(s)*(1.f/384.f);
    float q = 0.f;
    #pragma unroll
    for (int i=0;i<6;i++){ float d = v[i]-mu; q += d*d; }
    float rs = rsqrtf(wsum(q)*(1.f/384.f) + 1e-5f);
    if (MODE==0){
        u16* op = (u16*)out + (long long)row*384;
        #pragma unroll
        for (int i=0;i<6;i++){ int c = lane + i*64; op[c] = f2b((v[i]-mu)*rs*g[c] + b[c]); }
    } else {
        float* op = (float*)out + (long long)row*384;
        #pragma unroll
        for (int i=0;i<6;i++){ int c = lane + i*64; op[c] = (v[i]-mu)*rs*g[c] + b[c]; }
    }
}

// patch-embed: sum 2 parts -> LN -> + pos -> h (f32)
__global__ __launch_bounds__(256) void k_pe_ln(const float* __restrict__ parts,
        const float* __restrict__ g, const float* __restrict__ b,
        const float* __restrict__ pos, float* __restrict__ h){
    int row = blockIdx.x*4 + (threadIdx.x>>6);
    int lane = threadIdx.x & 63;
    float v[6]; float s = 0.f;
    #pragma unroll
    for (int i=0;i<6;i++){
        int c = lane + i*64;
        float t = parts[(long long)row*384 + c] + parts[(long long)MP*384 + (long long)row*384 + c];
        v[i] = t; s += t;
    }
    float mu = wsum(s)*(1.f/384.f);
    float q = 0.f;
    #pragma unroll
    for (int i=0;i<6;i++){ float d = v[i]-mu; q += d*d; }
    float rs = rsqrtf(wsum(q)*(1.f/384.f) + 1e-5f);
    int t = row % 196;
    const float* pp = pos + (long long)t*384;
    float* op = h + (long long)row*384;
    #pragma unroll
    for (int i=0;i<6;i++){ int c = lane + i*64; op[c] = (v[i]-mu)*rs*g[c] + b[c] + pp[c]; }
}

// sum 4 parts -> LN(sn) -> h += -> LN(n2) -> hn bf16
__global__ __launch_bounds__(256) void k_sn_ln(const float* __restrict__ parts,
        const float* __restrict__ sg, const float* __restrict__ sb,
        float* __restrict__ h,
        const float* __restrict__ n2g, const float* __restrict__ n2b,
        u16* __restrict__ hn2){
    int row = blockIdx.x*4 + (threadIdx.x>>6);
    int lane = threadIdx.x & 63;
    float v[6]; float s = 0.f;
    #pragma unroll
    for (int i=0;i<6;i++){
        int c = lane + i*64;
        long long o = (long long)row*384 + c;
        float t = parts[o] + parts[(long long)MP*384 + o] + parts[2LL*MP*384 + o] + parts[3LL*MP*384 + o];
        v[i] = t; s += t;
    }
    float mu = wsum(s)*(1.f/384.f);
    float q = 0.f;
    #pragma unroll
    for (int i=0;i<6;i++){ float d = v[i]-mu; q += d*d; }
    float rs = rsqrtf(wsum(q)*(1.f/384.f) + 1e-5f);
    float* hp = h + (long long)row*384;
    float hv[6]; float s2 = 0.f;
    #pragma unroll
    for (int i=0;i<6;i++){
        int c = lane + i*64;
        float nv = hp[c] + (v[i]-mu)*rs*sg[c] + sb[c];
        hp[c] = nv; hv[i] = nv; s2 += nv;
    }
    float mu2 = wsum(s2)*(1.f/384.f);
    float q2 = 0.f;
    #pragma unroll
    for (int i=0;i<6;i++){ float d = hv[i]-mu2; q2 += d*d; }
    float rs2 = rsqrtf(wsum(q2)*(1.f/384.f) + 1e-5f);
    u16* op = hn2 + (long long)row*384;
    #pragma unroll
    for (int i=0;i<6;i++){ int c = lane + i*64; op[c] = f2b((hv[i]-mu2)*rs2*n2g[c] + n2b[c]); }
}

// gated SiLU*sigmoid + per-768 LN : zg(MP,6144)bf16 -> lnz(MP,3072)bf16
__global__ __launch_bounds__(256) void k_gate_ln(const u16* __restrict__ zg,
        const float* __restrict__ lag, const float* __restrict__ lab, u16* __restrict__ lnz){
    int unit = blockIdx.x*4 + (threadIdx.x>>6);
    int lane = threadIdx.x & 63;
    int row = unit >> 2, dir = unit & 3;
    const u16* zp = zg + (long long)row*6144 + dir*1536;
    float gated[12]; float s = 0.f;
    #pragma unroll
    for (int p=0;p<3;p++){
        int j = p*256 + lane*4;
        ushort4 zv = *reinterpret_cast<const ushort4*>(zp + j);
        ushort4 gv = *reinterpret_cast<const ushort4*>(zp + 768 + j);
        const u16* za = (const u16*)&zv;
        const u16* ga = (const u16*)&gv;
        #pragma unroll
        for (int qq=0;qq<4;qq++){
            float zf = b2f(za[qq]);
            float gf = b2f(ga[qq]);
            float val = zf/(1.f+__expf(-zf)) * (1.f/(1.f+__expf(-gf)));
            gated[p*4+qq] = val; s += val;
        }
    }
    float mu = wsum(s)*(1.f/768.f);
    float q = 0.f;
    #pragma unroll
    for (int i=0;i<12;i++){ float d = gated[i]-mu; q += d*d; }
    float rs = rsqrtf(wsum(q)*(1.f/768.f) + 1e-5f);
    const float* gg = lag + dir*768;
    const float* bb = lab + dir*768;
    u16* op = lnz + (long long)row*3072 + dir*768;
    #pragma unroll
    for (int p=0;p<3;p++){
        int j = p*256 + lane*4;
        ushort4 ov;
        u16* oa = (u16*)&ov;
        #pragma unroll
        for (int qq=0;qq<4;qq++)
            oa[qq] = f2b((gated[p*4+qq]-mu)*rs*gg[j+qq] + bb[j+qq]);
        *reinterpret_cast<ushort4*>(op + j) = ov;
    }
}

// --------------------------------------------------------------------------
extern "C" void kernel_launch(void* const* d_in, const int* in_sizes, int n_in,
                              void* d_out, int out_size, void* d_ws, size_t ws_size,
                              hipStream_t stream)
{
    const float* x      = (const float*)d_in[0];
    const float* patch_w= (const float*)d_in[1];
    const float* patch_b= (const float*)d_in[2];
    const float* pe_g   = (const float*)d_in[3];
    const float* pe_b   = (const float*)d_in[4];
    const float* pos    = (const float*)d_in[5];
    const float* n1_g   = (const float*)d_in[6];
    const float* n1_b   = (const float*)d_in[7];
    const float* pi_w   = (const float*)d_in[8];
    const float* pi_b   = (const float*)d_in[9];
    const float* po_w   = (const float*)d_in[10];
    const float* po_b   = (const float*)d_in[11];
    const float* la_g   = (const float*)d_in[12];
    const float* la_b   = (const float*)d_in[13];
    const float* mg_w   = (const float*)d_in[14];
    const float* mg_b   = (const float*)d_in[15];
    const float* sn_g   = (const float*)d_in[16];
    const float* sn_b   = (const float*)d_in[17];
    const float* n2_g   = (const float*)d_in[18];
    const float* n2_b   = (const float*)d_in[19];
    const float* m1_w   = (const float*)d_in[20];
    const float* m1_b   = (const float*)d_in[21];
    const float* m2_w   = (const float*)d_in[22];
    const float* m2_b   = (const float*)d_in[23];
    const float* fin_g  = (const float*)d_in[24];
    const float* fin_b  = (const float*)d_in[25];

    char* wptr = (char*)d_ws;
    auto carve = [&](long long elems, int esz)->void*{
        void* p = (void*)wptr;
        wptr += ((elems*(long long)esz + 255)/256)*256;
        return p;
    };

    u16* wt_pi = (u16*)carve(28311552, 2);   // (12*4) x (1536,384)
    u16* wt_po = (u16*)carve(14155776, 2);   // (12*4) x (384,768)
    u16* wt_mg = (u16*)carve(7077888, 2);    // 12 x (384,1536)
    u16* wt_m1 = (u16*)carve(7077888, 2);    // 12 x (1536,384)
    u16* wt_m2 = (u16*)carve(7077888, 2);    // 12 x (384,1536)
    u16* wt_pe = (u16*)carve(294912, 2);     // (384,768)
    float* h      = (float*)carve((long long)MP*384, 4);
    float* parts  = (float*)carve(4LL*MP*384, 4);
    u16* patches  = (u16*)carve((long long)MP*768, 2);
    u16* hn       = (u16*)carve((long long)MP*384, 2);
    u16* zg       = (u16*)carve((long long)MP*6144, 2);
    u16* lnz      = (u16*)carve((long long)MP*3072, 2);
    u16* outs     = (u16*)carve((long long)MP*1536, 2);

    dim3 blk(256);

    // weight transposes (fp32 -> bf16, B^T layout)
    k_transpose<<<dim3(48,12,48), blk, 0, stream>>>(pi_w,   wt_pi, 384, 1536);
    k_transpose<<<dim3(12,24,48), blk, 0, stream>>>(po_w,   wt_po, 768, 384);
    k_transpose<<<dim3(12,48,12), blk, 0, stream>>>(mg_w,   wt_mg, 1536, 384);
    k_transpose<<<dim3(48,12,12), blk, 0, stream>>>(m1_w,   wt_m1, 384, 1536);
    k_transpose<<<dim3(12,48,12), blk, 0, stream>>>(m2_w,   wt_m2, 1536, 384);
    k_transpose<<<dim3(12,24,1),  blk, 0, stream>>>(patch_w,wt_pe, 768, 384);

    // patch embed (split-K=2 into parts, bias folded into z0 part)
    k_patches<<<dim3(MP*768/256), blk, 0, stream>>>(x, patches);
    gemm_tn<2><<<dim3(3,25,2), blk, 0, stream>>>(patches, 768, 0, wt_pe, 0, 768, 384,
                                                 patch_b, 0, parts, 384, MP*384, 384);
    k_pe_ln<<<dim3(MP/4), blk, 0, stream>>>(parts, pe_g, pe_b, pos, h);

    // LN1 for layer 0
    k_addln<0><<<dim3(MP/4), blk, 0, stream>>>(h, nullptr, 0, n1_g, n1_b, hn);

    for (int l=0; l<L_; ++l){
        // 4 direction input projections (batched over z=dir)
        gemm_tn<0><<<dim3(12,25,4), blk, 0, stream>>>(hn, 384, 0,
            wt_pi + (long long)l*4*589824, 589824, 384, 0,
            pi_b + (long long)l*4*1536, 1536,
            zg, 6144, 1536, 384);
        k_gate_ln<<<dim3(MP), blk, 0, stream>>>(zg, la_g + (long long)l*3072, la_b + (long long)l*3072, lnz);
        // 4 output projections (batched over z=dir)
        gemm_tn<0><<<dim3(3,25,4), blk, 0, stream>>>(lnz, 3072, 768,
            wt_po + (long long)l*4*294912, 294912, 768, 0,
            po_b + (long long)l*4*384, 384,
            outs, 1536, 384, 768);
        // merge: split-K=4 into parts
        gemm_tn<2><<<dim3(3,25,4), blk, 0, stream>>>(outs, 1536, 0,
            wt_mg + (long long)l*589824, 0, 1536, 384,
            mg_b + (long long)l*384, 0,
            parts, 384, MP*384, 1536/4);
        k_sn_ln<<<dim3(MP/4), blk, 0, stream>>>(parts, sn_g + l*384, sn_b + l*384,
                                                h, n2_g + l*384, n2_b + l*384, hn);
        // MLP up + GELU
        gemm_tn<1><<<dim3(12,25,1), blk, 0, stream>>>(hn, 384, 0,
            wt_m1 + (long long)l*589824, 0, 384, 0,
            m1_b + (long long)l*1536, 0,
            outs, 1536, 0, 384);
        // MLP down: split-K=4 into parts
        gemm_tn<2><<<dim3(3,25,4), blk, 0, stream>>>(outs, 1536, 0,
            wt_m2 + (long long)l*589824, 0, 1536, 384,
            m2_b + (long long)l*384, 0,
            parts, 384, MP*384, 1536/4);
        // h += sum(parts); LN(n1[l+1]) -> hn   (or final LN -> d_out)
        if (l < L_-1)
            k_addln<0><<<dim3(MP/4), blk, 0, stream>>>(h, parts, 4,
                n1_g + (l+1)*384, n1_b + (l+1)*384, hn);
        else
            k_addln<1><<<dim3(NTOK/4), blk, 0, stream>>>(h, parts, 4,
                fin_g, fin_b, (float*)d_out);
    }
}

// Round 3
// 1803.926 us; speedup vs baseline: 1.2104x; 1.1017x over previous
//
#include <hip/hip_runtime.h>
#include <math.h>

typedef unsigned short u16;
typedef __bf16 bf16x8 __attribute__((ext_vector_type(8)));
typedef float f32x4 __attribute__((ext_vector_type(4)));

#define L_   12
#define NTOK 3136
#define MP   3200

__device__ __forceinline__ float b2f(u16 v){ return __builtin_bit_cast(float, (unsigned)v<<16); }
__device__ __forceinline__ u16 f2b(float f){
    unsigned u = __builtin_bit_cast(unsigned, f);
    u += 0x7fffu + ((u>>16)&1u);
    return (u16)(u>>16);
}
__device__ __forceinline__ float wsum(float v){
    #pragma unroll
    for (int o=32;o;o>>=1) v += __shfl_xor(v,o);
    return v;
}
__device__ __forceinline__ void gl_lds16(const void* g, void* l){
    __builtin_amdgcn_global_load_lds(
        (const __attribute__((address_space(1))) void*)g,
        (__attribute__((address_space(3))) void*)l, 16, 0, 0);
}

// ---------------- weight transpose + fp32->bf16 convert -------------------
// src: z-th (R,C) f32 block -> dst: z-th (C,R) bf16 block
__global__ __launch_bounds__(256) void k_transpose(const float* __restrict__ src,
                                                   u16* __restrict__ dst, int R, int C){
    __shared__ float t[32][33];
    long long base = (long long)blockIdx.z * R * C;
    int c0 = blockIdx.x<<5, r0 = blockIdx.y<<5;
    int tx = threadIdx.x & 31, ty = threadIdx.x >> 5;
    #pragma unroll
    for (int i=0;i<32;i+=8)
        t[ty+i][tx] = src[base + (long long)(r0+ty+i)*C + c0 + tx];
    __syncthreads();
    #pragma unroll
    for (int i=0;i<32;i+=8)
        dst[base + (long long)(c0+ty+i)*R + r0 + tx] = f2b(t[tx][ty+i]);
}

// plain fp32 -> bf16 convert (no transpose)
__global__ __launch_bounds__(256) void k_cvt(const float4* __restrict__ src,
                                             ushort4* __restrict__ dst, int n4){
    int i = blockIdx.x*256 + threadIdx.x;
    if (i < n4){
        float4 v = src[i];
        ushort4 o; o.x=f2b(v.x); o.y=f2b(v.y); o.z=f2b(v.z); o.w=f2b(v.w);
        dst[i] = o;
    }
}

// bias fold for fused po+mg: bcp[z=(l,d)][i] = sum_k po_b[l,d,k]*mg_w[l,d*384+k,i]
__global__ __launch_bounds__(384) void k_bc(const float* __restrict__ po_b,
                                            const float* __restrict__ mg_w,
                                            float* __restrict__ bcp){
    int z = blockIdx.x;          // l*4+d
    int i = threadIdx.x;         // 0..383
    const float* pb = po_b + (long long)z*384;
    const float* mw = mg_w + (long long)z*384*384;
    float s = 0.f;
    for (int k=0;k<384;k++) s = fmaf(pb[k], mw[(long long)k*384 + i], s);
    bcp[(long long)z*384 + i] = s;
}

// ---------------- patch extraction ---------------------------------------
__global__ __launch_bounds__(256) void k_patches(const float* __restrict__ x, u16* __restrict__ out){
    int idx = blockIdx.x*256 + threadIdx.x;
    int row = idx / 768, col = idx - row*768;
    float v = 0.f;
    if (row < NTOK){
        int b = row / 196, t = row - b*196;
        int gi = t / 14, gj = t - gi*14;
        int c = col >> 8, rem = col & 255, pi = rem >> 4, pj = rem & 15;
        v = x[((long long)(b*3 + c)*224 + gi*16 + pi)*224 + gj*16 + pj];
    }
    out[idx] = f2b(v);
}

// ---------------- GEMM: C = A(M,K)bf16 @ Bt(N,K)bf16 (+bias) --------------
// z split as zh = z>>zshift, zl = z & ((1<<zshift)-1); element offsets per zh/zl.
// EPI: 0 = bf16 out, 1 = bf16 out + exact GELU, 2 = f32 out
// splitBias: bias added only when zl==0 (split-K); else every z.
// LDS double-buffered, stage via global_load_lds with XOR-swizzled source cols.
template<int EPI>
__global__ __launch_bounds__(256) void gemm_tn(
    const u16* __restrict__ A, int lda, long long aSh, long long aSl,
    const u16* __restrict__ Bt, int ldb, long long bSh, long long bSl,
    const float* __restrict__ bias, long long biasSh, int splitBias,
    void* __restrict__ Cbase, int ldc, long long cSh, long long cSl,
    int K, int zshift)
{
    int z = blockIdx.z;
    int zh = z >> zshift, zl = z - (zh << zshift);
    const u16* Az  = A  + zh*aSh + zl*aSl;
    const u16* Btz = Bt + zh*bSh + zl*bSl;
    bool addb = bias && (!splitBias || zl == 0);
    long long cOff = zh*cSh + zl*cSl;
    int m0 = blockIdx.y*128, n0 = blockIdx.x*128;

    __shared__ u16 As[2][8192];
    __shared__ u16 Bs[2][8192];

    int tid = threadIdx.x;
    int lane = tid & 63;
    int w = tid >> 6;
    int wm = w >> 1, wn = w & 1;
    int rsub = lane >> 3, csub = lane & 7;
    int scol = ((csub ^ rsub) << 3);     // swizzled source column (elements)

    const u16* ga[4]; const u16* gb[4]; int lo[4];
    #pragma unroll
    for (int j=0;j<4;j++){
        int r = w*32 + j*8 + rsub;
        ga[j] = Az  + (long long)(m0 + r)*lda + scol;
        gb[j] = Btz + (long long)(n0 + r)*ldb + scol;
        lo[j] = (w*32 + j*8)*64;
    }

    f32x4 acc[4][4];
    #pragma unroll
    for (int m=0;m<4;m++)
        #pragma unroll
        for (int n=0;n<4;n++) acc[m][n] = (f32x4){0.f,0.f,0.f,0.f};

    int nkt = K >> 6;
    // prologue: stage tile 0 into buf 0
    #pragma unroll
    for (int j=0;j<4;j++){ gl_lds16(ga[j], &As[0][lo[j]]); gl_lds16(gb[j], &Bs[0][lo[j]]); }
    __syncthreads();

    int cur = 0;
    for (int kt=0; kt<nkt; ++kt){
        if (kt+1 < nkt){
            int ko = (kt+1) << 6;
            #pragma unroll
            for (int j=0;j<4;j++){
                gl_lds16(ga[j] + ko, &As[cur^1][lo[j]]);
                gl_lds16(gb[j] + ko, &Bs[cur^1][lo[j]]);
            }
        }
        const char* as = (const char*)As[cur];
        const char* bs = (const char*)Bs[cur];
        int kxor = (lane & 7) << 4;
        #pragma unroll
        for (int kk=0; kk<2; ++kk){
            bf16x8 af[4], bfr[4];
            int kb = ((kk*32 + ((lane>>4)<<3))*2) ^ kxor;
            #pragma unroll
            for (int m=0;m<4;m++){
                int r = wm*64 + m*16 + (lane&15);
                af[m] = *reinterpret_cast<const bf16x8*>(as + r*128 + kb);
            }
            #pragma unroll
            for (int n=0;n<4;n++){
                int r = wn*64 + n*16 + (lane&15);
                bfr[n] = *reinterpret_cast<const bf16x8*>(bs + r*128 + kb);
            }
            #pragma unroll
            for (int m=0;m<4;m++)
                #pragma unroll
                for (int n=0;n<4;n++)
                    acc[m][n] = __builtin_amdgcn_mfma_f32_16x16x32_bf16(af[m], bfr[n], acc[m][n], 0,0,0);
        }
        __syncthreads();   // drains vmcnt(0)+lgkmcnt(0): next tile staged & safe to overwrite cur
        cur ^= 1;
    }

    int rbase = m0 + wm*64;
    int nbase = n0 + wn*64;
    #pragma unroll
    for (int m=0;m<4;m++){
        #pragma unroll
        for (int n=0;n<4;n++){
            int ncol = nbase + n*16 + (lane&15);
            float bv = addb ? bias[zh*biasSh + ncol] : 0.f;
            #pragma unroll
            for (int r4=0;r4<4;r4++){
                int row = rbase + m*16 + ((lane>>4)<<2) + r4;
                float v = acc[m][n][r4] + bv;
                long long idx = (long long)row*ldc + ncol + cOff;
                if (EPI==0)      ((u16*)Cbase)[idx] = f2b(v);
                else if (EPI==1){
                    float gl = 0.5f*v*(1.f + erff(v*0.70710678118f));
                    ((u16*)Cbase)[idx] = f2b(gl);
                }
                else             ((float*)Cbase)[idx] = v;
            }
        }
    }
}

// -------- h += sum(parts[np]); LN -> out. MODE 0: bf16 out + update h. MODE 1: f32 out.
template<int MODE>
__global__ __launch_bounds__(256) void k_addln(float* __restrict__ h,
        const float* __restrict__ parts, int np,
        const float* __restrict__ g, const float* __restrict__ b, void* __restrict__ out){
    int row = blockIdx.x*4 + (threadIdx.x>>6);
    int lane = threadIdx.x & 63;
    float* hp = h + (long long)row*384;
    float v[6]; float s = 0.f;
    #pragma unroll
    for (int i=0;i<6;i++){
        int c = lane + i*64;
        float t = hp[c];
        for (int p=0;p<np;p++) t += parts[(long long)p*MP*384 + (long long)row*384 + c];
        v[i] = t; s += t;
    }
    if (MODE==0 && np){
        #pragma unroll
        for (int i=0;i<6;i++) hp[lane + i*64] = v[i];
    }
    float mu = wsum(s)*(1.f/384.f);
    float q = 0.f;
    #pragma unroll
    for (int i=0;i<6;i++){ float d = v[i]-mu; q += d*d; }
    float rs = rsqrtf(wsum(q)*(1.f/384.f) + 1e-5f);
    if (MODE==0){
        u16* op = (u16*)out + (long long)row*384;
        #pragma unroll
        for (int i=0;i<6;i++){ int c = lane + i*64; op[c] = f2b((v[i]-mu)*rs*g[c] + b[c]); }
    } else {
        float* op = (float*)out + (long long)row*384;
        #pragma unroll
        for (int i=0;i<6;i++){ int c = lane + i*64; op[c] = (v[i]-mu)*rs*g[c] + b[c]; }
    }
}

// patch-embed: sum 2 parts -> LN -> + pos -> h (f32)
__global__ __launch_bounds__(256) void k_pe_ln(const float* __restrict__ parts,
        const float* __restrict__ g, const float* __restrict__ b,
        const float* __restrict__ pos, float* __restrict__ h){
    int row = blockIdx.x*4 + (threadIdx.x>>6);
    int lane = threadIdx.x & 63;
    float v[6]; float s = 0.f;
    #pragma unroll
    for (int i=0;i<6;i++){
        int c = lane + i*64;
        float t = parts[(long long)row*384 + c] + parts[(long long)MP*384 + (long long)row*384 + c];
        v[i] = t; s += t;
    }
    float mu = wsum(s)*(1.f/384.f);
    float q = 0.f;
    #pragma unroll
    for (int i=0;i<6;i++){ float d = v[i]-mu; q += d*d; }
    float rs = rsqrtf(wsum(q)*(1.f/384.f) + 1e-5f);
    int t = row % 196;
    const float* pp = pos + (long long)t*384;
    float* op = h + (long long)row*384;
    #pragma unroll
    for (int i=0;i<6;i++){ int c = lane + i*64; op[c] = (v[i]-mu)*rs*g[c] + b[c] + pp[c]; }
}

// sum 8 parts + bias terms -> LN(sn) -> h += -> LN(n2) -> hn bf16
__global__ __launch_bounds__(256) void k_sn_ln(const float* __restrict__ parts,
        const float* __restrict__ bcp, const float* __restrict__ mgb,
        const float* __restrict__ sg, const float* __restrict__ sb,
        float* __restrict__ h,
        const float* __restrict__ n2g, const float* __restrict__ n2b,
        u16* __restrict__ hn2){
    int row = blockIdx.x*4 + (threadIdx.x>>6);
    int lane = threadIdx.x & 63;
    float v[6]; float s = 0.f;
    #pragma unroll
    for (int i=0;i<6;i++){
        int c = lane + i*64;
        long long o = (long long)row*384 + c;
        float t = mgb[c] + bcp[c] + bcp[384+c] + bcp[768+c] + bcp[1152+c];
        #pragma unroll
        for (int p=0;p<8;p++) t += parts[(long long)p*MP*384 + o];
        v[i] = t; s += t;
    }
    float mu = wsum(s)*(1.f/384.f);
    float q = 0.f;
    #pragma unroll
    for (int i=0;i<6;i++){ float d = v[i]-mu; q += d*d; }
    float rs = rsqrtf(wsum(q)*(1.f/384.f) + 1e-5f);
    float* hp = h + (long long)row*384;
    float hv[6]; float s2 = 0.f;
    #pragma unroll
    for (int i=0;i<6;i++){
        int c = lane + i*64;
        float nv = hp[c] + (v[i]-mu)*rs*sg[c] + sb[c];
        hp[c] = nv; hv[i] = nv; s2 += nv;
    }
    float mu2 = wsum(s2)*(1.f/384.f);
    float q2 = 0.f;
    #pragma unroll
    for (int i=0;i<6;i++){ float d = hv[i]-mu2; q2 += d*d; }
    float rs2 = rsqrtf(wsum(q2)*(1.f/384.f) + 1e-5f);
    u16* op = hn2 + (long long)row*384;
    #pragma unroll
    for (int i=0;i<6;i++){ int c = lane + i*64; op[c] = f2b((hv[i]-mu2)*rs2*n2g[c] + n2b[c]); }
}

// gated SiLU*sigmoid + per-768 LN : zg(MP,6144)bf16 -> lnz(MP,3072)bf16
__global__ __launch_bounds__(256) void k_gate_ln(const u16* __restrict__ zg,
        const float* __restrict__ lag, const float* __restrict__ lab, u16* __restrict__ lnz){
    int unit = blockIdx.x*4 + (threadIdx.x>>6);
    int lane = threadIdx.x & 63;
    int row = unit >> 2, dir = unit & 3;
    const u16* zp = zg + (long long)row*6144 + dir*1536;
    float gated[12]; float s = 0.f;
    #pragma unroll
    for (int p=0;p<3;p++){
        int j = p*256 + lane*4;
        ushort4 zv = *reinterpret_cast<const ushort4*>(zp + j);
        ushort4 gv = *reinterpret_cast<const ushort4*>(zp + 768 + j);
        const u16* za = (const u16*)&zv;
        const u16* ga = (const u16*)&gv;
        #pragma unroll
        for (int qq=0;qq<4;qq++){
            float zf = b2f(za[qq]);
            float gf = b2f(ga[qq]);
            float val = zf/(1.f+__expf(-zf)) * (1.f/(1.f+__expf(-gf)));
            gated[p*4+qq] = val; s += val;
        }
    }
    float mu = wsum(s)*(1.f/768.f);
    float q = 0.f;
    #pragma unroll
    for (int i=0;i<12;i++){ float d = gated[i]-mu; q += d*d; }
    float rs = rsqrtf(wsum(q)*(1.f/768.f) + 1e-5f);
    const float* gg = lag + dir*768;
    const float* bb = lab + dir*768;
    u16* op = lnz + (long long)row*3072 + dir*768;
    #pragma unroll
    for (int p=0;p<3;p++){
        int j = p*256 + lane*4;
        ushort4 ov;
        u16* oa = (u16*)&ov;
        #pragma unroll
        for (int qq=0;qq<4;qq++)
            oa[qq] = f2b((gated[p*4+qq]-mu)*rs*gg[j+qq] + bb[j+qq]);
        *reinterpret_cast<ushort4*>(op + j) = ov;
    }
}

// --------------------------------------------------------------------------
extern "C" void kernel_launch(void* const* d_in, const int* in_sizes, int n_in,
                              void* d_out, int out_size, void* d_ws, size_t ws_size,
                              hipStream_t stream)
{
    const float* x      = (const float*)d_in[0];
    const float* patch_w= (const float*)d_in[1];
    const float* patch_b= (const float*)d_in[2];
    const float* pe_g   = (const float*)d_in[3];
    const float* pe_b   = (const float*)d_in[4];
    const float* pos    = (const float*)d_in[5];
    const float* n1_g   = (const float*)d_in[6];
    const float* n1_b   = (const float*)d_in[7];
    const float* pi_w   = (const float*)d_in[8];
    const float* pi_b   = (const float*)d_in[9];
    const float* po_w   = (const float*)d_in[10];
    const float* po_b   = (const float*)d_in[11];
    const float* la_g   = (const float*)d_in[12];
    const float* la_b   = (const float*)d_in[13];
    const float* mg_w   = (const float*)d_in[14];
    const float* mg_b   = (const float*)d_in[15];
    const float* sn_g   = (const float*)d_in[16];
    const float* sn_b   = (const float*)d_in[17];
    const float* n2_g   = (const float*)d_in[18];
    const float* n2_b   = (const float*)d_in[19];
    const float* m1_w   = (const float*)d_in[20];
    const float* m1_b   = (const float*)d_in[21];
    const float* m2_w   = (const float*)d_in[22];
    const float* m2_b   = (const float*)d_in[23];
    const float* fin_g  = (const float*)d_in[24];
    const float* fin_b  = (const float*)d_in[25];

    char* wptr = (char*)d_ws;
    auto carve = [&](long long elems, int esz)->void*{
        void* p = (void*)wptr;
        wptr += ((elems*(long long)esz + 255)/256)*256;
        return p;
    };

    u16* wt_pi  = (u16*)carve(28311552, 2);  // 48 x (1536,384)  = per-l (6144,384)
    u16* wt_mgr = (u16*)carve(7077888, 2);   // 48 x (384,384)   M^T blocks
    u16* wt_m1  = (u16*)carve(7077888, 2);   // 12 x (1536,384)
    u16* wt_m2  = (u16*)carve(7077888, 2);   // 12 x (384,1536)
    u16* wt_pe  = (u16*)carve(294912, 2);    // (384,768)
    u16* po_bf  = (u16*)carve(14155776, 2);  // po_w as bf16, (48,768,384)
    u16* WcT    = (u16*)carve(14155776, 2);  // 12 x (384,3072) fused po@mg, transposed
    float* bcp  = (float*)carve(48*384, 4);  // po_b @ mg_w partials
    float* h    = (float*)carve((long long)MP*384, 4);
    float* parts= (float*)carve(8LL*MP*384, 4);
    u16* patches= (u16*)carve((long long)MP*768, 2);
    u16* hn     = (u16*)carve((long long)MP*384, 2);
    u16* zg     = (u16*)carve((long long)MP*6144, 2);
    u16* lnz    = (u16*)carve((long long)MP*3072, 2);
    u16* outs   = (u16*)carve((long long)MP*1536, 2);

    dim3 blk(256);

    // ---- one-time weight prep ----
    k_transpose<<<dim3(48,12,48), blk, 0, stream>>>(pi_w,   wt_pi, 384, 1536);
    k_transpose<<<dim3(12,12,48), blk, 0, stream>>>(mg_w,   wt_mgr, 384, 384);
    k_transpose<<<dim3(48,12,12), blk, 0, stream>>>(m1_w,   wt_m1, 384, 1536);
    k_transpose<<<dim3(12,48,12), blk, 0, stream>>>(m2_w,   wt_m2, 1536, 384);
    k_transpose<<<dim3(12,24,1),  blk, 0, stream>>>(patch_w,wt_pe, 768, 384);
    k_cvt<<<dim3(13824), blk, 0, stream>>>((const float4*)po_w, (ushort4*)po_bf, 3538944);
    k_bc<<<dim3(48), dim3(384), 0, stream>>>(po_b, mg_w, bcp);
    // WcT[l,dir] (384,768) = M^T @ P^T ; stored interleaved as per-l (384,3072)
    gemm_tn<0><<<dim3(6,3,48), blk, 0, stream>>>(
        wt_mgr, 384, 589824LL, 147456LL,
        po_bf,  384, 1179648LL, 294912LL,
        nullptr, 0, 0,
        WcT, 3072, 1179648LL, 768LL, 384, 2);

    // ---- patch embed ----
    k_patches<<<dim3(MP*768/256), blk, 0, stream>>>(x, patches);
    gemm_tn<2><<<dim3(3,25,2), blk, 0, stream>>>(
        patches, 768, 0, 384,
        wt_pe,   768, 0, 384,
        patch_b, 0, 1,
        parts, 384, 0, (long long)MP*384, 384, 1);
    k_pe_ln<<<dim3(MP/4), blk, 0, stream>>>(parts, pe_g, pe_b, pos, h);
    k_addln<0><<<dim3(MP/4), blk, 0, stream>>>(h, nullptr, 0, n1_g, n1_b, hn);

    for (int l=0; l<L_; ++l){
        // input projections, all 4 dirs as one GEMM: hn(MP,384) @ (384,6144)
        gemm_tn<0><<<dim3(48,25,1), blk, 0, stream>>>(
            hn, 384, 0, 0,
            wt_pi + (long long)l*2359296, 384, 0, 0,
            pi_b + (long long)l*6144, 0, 0,
            zg, 6144, 0, 0, 384, 0);
        k_gate_ln<<<dim3(MP), blk, 0, stream>>>(zg, la_g + (long long)l*3072, la_b + (long long)l*3072, lnz);
        // fused po+mg: lnz(MP,3072) @ Wc(3072,384), split-K=8
        gemm_tn<2><<<dim3(3,25,8), blk, 0, stream>>>(
            lnz, 3072, 0, 384,
            WcT + (long long)l*1179648, 3072, 0, 384,
            nullptr, 0, 0,
            parts, 384, 0, (long long)MP*384, 384, 3);
        k_sn_ln<<<dim3(MP/4), blk, 0, stream>>>(parts, bcp + (long long)l*1536, mg_b + l*384,
                                                sn_g + l*384, sn_b + l*384,
                                                h, n2_g + l*384, n2_b + l*384, hn);
        // MLP up + GELU
        gemm_tn<1><<<dim3(12,25,1), blk, 0, stream>>>(
            hn, 384, 0, 0,
            wt_m1 + (long long)l*589824, 384, 0, 0,
            m1_b + (long long)l*1536, 0, 0,
            outs, 1536, 0, 0, 384, 0);
        // MLP down: split-K=4
        gemm_tn<2><<<dim3(3,25,4), blk, 0, stream>>>(
            outs, 1536, 0, 384,
            wt_m2 + (long long)l*589824, 1536, 0, 384,
            m2_b + l*384, 0, 1,
            parts, 384, 0, (long long)MP*384, 384, 2);
        if (l < L_-1)
            k_addln<0><<<dim3(MP/4), blk, 0, stream>>>(h, parts, 4,
                n1_g + (l+1)*384, n1_b + (l+1)*384, hn);
        else
            k_addln<1><<<dim3(NTOK/4), blk, 0, stream>>>(h, parts, 4,
                fin_g, fin_b, (float*)d_out);
    }
}

// Round 4
// 1700.860 us; speedup vs baseline: 1.2838x; 1.0606x over previous
//
#include <hip/hip_runtime.h>
#include <math.h>

typedef unsigned short u16;
typedef __bf16 bf16x8 __attribute__((ext_vector_type(8)));
typedef float f32x4 __attribute__((ext_vector_type(4)));

#define L_   12
#define NTOK 3136
#define MP   3200

__device__ __forceinline__ float b2f(u16 v){ return __builtin_bit_cast(float, (unsigned)v<<16); }
__device__ __forceinline__ u16 f2b(float f){
    unsigned u = __builtin_bit_cast(unsigned, f);
    u += 0x7fffu + ((u>>16)&1u);
    return (u16)(u>>16);
}
__device__ __forceinline__ float wsum(float v){
    #pragma unroll
    for (int o=32;o;o>>=1) v += __shfl_xor(v,o);
    return v;
}
__device__ __forceinline__ void gl_lds16(const void* g, void* l){
    __builtin_amdgcn_global_load_lds(
        (const __attribute__((address_space(1))) void*)g,
        (__attribute__((address_space(3))) void*)l, 16, 0, 0);
}

// ---------------- weight transpose + fp32->bf16 convert -------------------
__global__ __launch_bounds__(256) void k_transpose(const float* __restrict__ src,
                                                   u16* __restrict__ dst, int R, int C){
    __shared__ float t[32][33];
    long long base = (long long)blockIdx.z * R * C;
    int c0 = blockIdx.x<<5, r0 = blockIdx.y<<5;
    int tx = threadIdx.x & 31, ty = threadIdx.x >> 5;
    #pragma unroll
    for (int i=0;i<32;i+=8)
        t[ty+i][tx] = src[base + (long long)(r0+ty+i)*C + c0 + tx];
    __syncthreads();
    #pragma unroll
    for (int i=0;i<32;i+=8)
        dst[base + (long long)(c0+ty+i)*R + r0 + tx] = f2b(t[tx][ty+i]);
}

// plain fp32 -> bf16 convert
__global__ __launch_bounds__(256) void k_cvt(const float4* __restrict__ src,
                                             ushort4* __restrict__ dst, int n4){
    int i = blockIdx.x*256 + threadIdx.x;
    if (i < n4){
        float4 v = src[i];
        ushort4 o; o.x=f2b(v.x); o.y=f2b(v.y); o.z=f2b(v.z); o.w=f2b(v.w);
        dst[i] = o;
    }
}

// bias fold for fused po+mg
__global__ __launch_bounds__(384) void k_bc(const float* __restrict__ po_b,
                                            const float* __restrict__ mg_w,
                                            float* __restrict__ bcp){
    int z = blockIdx.x;
    int i = threadIdx.x;
    const float* pb = po_b + (long long)z*384;
    const float* mw = mg_w + (long long)z*384*384;
    float s = 0.f;
    for (int k=0;k<384;k++) s = fmaf(pb[k], mw[(long long)k*384 + i], s);
    bcp[(long long)z*384 + i] = s;
}

// ---------------- patch extraction ---------------------------------------
__global__ __launch_bounds__(256) void k_patches(const float* __restrict__ x, u16* __restrict__ out){
    int idx = blockIdx.x*256 + threadIdx.x;
    int row = idx / 768, col = idx - row*768;
    float v = 0.f;
    if (row < NTOK){
        int b = row / 196, t = row - b*196;
        int gi = t / 14, gj = t - gi*14;
        int c = col >> 8, rem = col & 255, pi = rem >> 4, pj = rem & 15;
        v = x[((long long)(b*3 + c)*224 + gi*16 + pi)*224 + gj*16 + pj];
    }
    out[idx] = f2b(v);
}

// ---------------- GEMM: C = A(M,K)bf16 @ Bt(N,K)bf16 (+bias) --------------
// Counted-vmcnt double-buffered pipeline (requires K%128==0 -> even nkt).
template<int EPI>
__global__ __launch_bounds__(256) void gemm_tn(
    const u16* __restrict__ A, int lda, long long aSh, long long aSl,
    const u16* __restrict__ Bt, int ldb, long long bSh, long long bSl,
    const float* __restrict__ bias, long long biasSh, int splitBias,
    void* __restrict__ Cbase, int ldc, long long cSh, long long cSl,
    int K, int zshift)
{
    int z = blockIdx.z;
    int zh = z >> zshift, zl = z - (zh << zshift);
    const u16* Az  = A  + zh*aSh + zl*aSl;
    const u16* Btz = Bt + zh*bSh + zl*bSl;
    bool addb = bias && (!splitBias || zl == 0);
    long long cOff = zh*cSh + zl*cSl;
    int m0 = blockIdx.y*128, n0 = blockIdx.x*128;

    __shared__ u16 As[2][8192];
    __shared__ u16 Bs[2][8192];

    int tid = threadIdx.x;
    int lane = tid & 63;
    int w = tid >> 6;
    int wm = w >> 1, wn = w & 1;
    int rsub = lane >> 3, csub = lane & 7;
    int scol = ((csub ^ rsub) << 3);     // swizzled source column (elements)
    int kxor = (lane & 7) << 4;

    const u16* ga[4]; const u16* gb[4]; int lo[4];
    #pragma unroll
    for (int j=0;j<4;j++){
        int r = w*32 + j*8 + rsub;
        ga[j] = Az  + (long long)(m0 + r)*lda + scol;
        gb[j] = Btz + (long long)(n0 + r)*ldb + scol;
        lo[j] = (w*32 + j*8)*64;
    }

    f32x4 acc[4][4];
    #pragma unroll
    for (int m=0;m<4;m++)
        #pragma unroll
        for (int n=0;n<4;n++) acc[m][n] = (f32x4){0.f,0.f,0.f,0.f};

    int nkt = K >> 6;   // must be even

    auto stage = [&](int ko, int p){
        #pragma unroll
        for (int j=0;j<4;j++){
            gl_lds16(ga[j] + ko, &As[p][lo[j]]);
            gl_lds16(gb[j] + ko, &Bs[p][lo[j]]);
        }
    };

    // prologue: stage tiles 0,1 (16 loads/thread outstanding)
    stage(0, 0);
    stage(64, 1);

    auto step = [&](int kt, int p){
        if (kt == nkt-1) asm volatile("s_waitcnt vmcnt(0)" ::: "memory");
        else             asm volatile("s_waitcnt vmcnt(8)" ::: "memory");
        __builtin_amdgcn_s_barrier();
        const char* as = (const char*)As[p];
        const char* bs = (const char*)Bs[p];
        bf16x8 af[2][4], bfr[2][4];
        #pragma unroll
        for (int kk=0; kk<2; ++kk){
            int kb = ((kk*32 + ((lane>>4)<<3))*2) ^ kxor;
            #pragma unroll
            for (int m=0;m<4;m++){
                int r = wm*64 + m*16 + (lane&15);
                af[kk][m] = *reinterpret_cast<const bf16x8*>(as + r*128 + kb);
            }
            #pragma unroll
            for (int n=0;n<4;n++){
                int r = wn*64 + n*16 + (lane&15);
                bfr[kk][n] = *reinterpret_cast<const bf16x8*>(bs + r*128 + kb);
            }
        }
        asm volatile("s_waitcnt lgkmcnt(0)" ::: "memory");
        __builtin_amdgcn_sched_barrier(0);
        __builtin_amdgcn_s_barrier();   // all waves done reading buf[p] -> safe to overwrite
        if (kt+2 < nkt) stage((kt+2)<<6, p);
        #pragma unroll
        for (int kk=0; kk<2; ++kk)
            #pragma unroll
            for (int m=0;m<4;m++)
                #pragma unroll
                for (int n=0;n<4;n++)
                    acc[m][n] = __builtin_amdgcn_mfma_f32_16x16x32_bf16(af[kk][m], bfr[kk][n], acc[m][n], 0,0,0);
    };

    for (int kt=0; kt<nkt; kt+=2){ step(kt, 0); step(kt+1, 1); }

    int rbase = m0 + wm*64;
    int nbase = n0 + wn*64;
    #pragma unroll
    for (int m=0;m<4;m++){
        #pragma unroll
        for (int n=0;n<4;n++){
            int ncol = nbase + n*16 + (lane&15);
            float bv = addb ? bias[zh*biasSh + ncol] : 0.f;
            #pragma unroll
            for (int r4=0;r4<4;r4++){
                int row = rbase + m*16 + ((lane>>4)<<2) + r4;
                float v = acc[m][n][r4] + bv;
                long long idx = (long long)row*ldc + ncol + cOff;
                if (EPI==0)      ((u16*)Cbase)[idx] = f2b(v);
                else if (EPI==1){
                    float gl = 0.5f*v*(1.f + erff(v*0.70710678118f));
                    ((u16*)Cbase)[idx] = f2b(gl);
                }
                else             ((float*)Cbase)[idx] = v;
            }
        }
    }
}

// -------- h += sum(parts[np]); LN -> out. MODE 0: bf16 out + update h. MODE 1: f32 out.
template<int MODE>
__global__ __launch_bounds__(256) void k_addln(float* __restrict__ h,
        const float* __restrict__ parts, int np,
        const float* __restrict__ g, const float* __restrict__ b, void* __restrict__ out){
    int row = blockIdx.x*4 + (threadIdx.x>>6);
    int lane = threadIdx.x & 63;
    float* hp = h + (long long)row*384;
    float v[6]; float s = 0.f;
    #pragma unroll
    for (int i=0;i<6;i++){
        int c = lane + i*64;
        float t = hp[c];
        for (int p=0;p<np;p++) t += parts[(long long)p*MP*384 + (long long)row*384 + c];
        v[i] = t; s += t;
    }
    if (MODE==0 && np){
        #pragma unroll
        for (int i=0;i<6;i++) hp[lane + i*64] = v[i];
    }
    float mu = wsum(s)*(1.f/384.f);
    float q = 0.f;
    #pragma unroll
    for (int i=0;i<6;i++){ float d = v[i]-mu; q += d*d; }
    float rs = rsqrtf(wsum(q)*(1.f/384.f) + 1e-5f);
    if (MODE==0){
        u16* op = (u16*)out + (long long)row*384;
        #pragma unroll
        for (int i=0;i<6;i++){ int c = lane + i*64; op[c] = f2b((v[i]-mu)*rs*g[c] + b[c]); }
    } else {
        float* op = (float*)out + (long long)row*384;
        #pragma unroll
        for (int i=0;i<6;i++){ int c = lane + i*64; op[c] = (v[i]-mu)*rs*g[c] + b[c]; }
    }
}

// patch-embed: sum 2 parts -> LN(pe) -> +pos -> h; then LN(n1[0]) -> hn bf16
__global__ __launch_bounds__(256) void k_pe_ln(const float* __restrict__ parts,
        const float* __restrict__ g, const float* __restrict__ b,
        const float* __restrict__ pos, float* __restrict__ h,
        const float* __restrict__ n1g, const float* __restrict__ n1b,
        u16* __restrict__ hn){
    int row = blockIdx.x*4 + (threadIdx.x>>6);
    int lane = threadIdx.x & 63;
    float v[6]; float s = 0.f;
    #pragma unroll
    for (int i=0;i<6;i++){
        int c = lane + i*64;
        float t = parts[(long long)row*384 + c] + parts[(long long)MP*384 + (long long)row*384 + c];
        v[i] = t; s += t;
    }
    float mu = wsum(s)*(1.f/384.f);
    float q = 0.f;
    #pragma unroll
    for (int i=0;i<6;i++){ float d = v[i]-mu; q += d*d; }
    float rs = rsqrtf(wsum(q)*(1.f/384.f) + 1e-5f);
    int t = row % 196;
    const float* pp = pos + (long long)t*384;
    float* op = h + (long long)row*384;
    float hv[6]; float s2 = 0.f;
    #pragma unroll
    for (int i=0;i<6;i++){
        int c = lane + i*64;
        float nv = (v[i]-mu)*rs*g[c] + b[c] + pp[c];
        op[c] = nv; hv[i] = nv; s2 += nv;
    }
    float mu2 = wsum(s2)*(1.f/384.f);
    float q2 = 0.f;
    #pragma unroll
    for (int i=0;i<6;i++){ float d = hv[i]-mu2; q2 += d*d; }
    float rs2 = rsqrtf(wsum(q2)*(1.f/384.f) + 1e-5f);
    u16* hp = hn + (long long)row*384;
    #pragma unroll
    for (int i=0;i<6;i++){ int c = lane + i*64; hp[c] = f2b((hv[i]-mu2)*rs2*n1g[c] + n1b[c]); }
}

// sum 8 parts + bias terms -> LN(sn) -> h += -> LN(n2) -> hn bf16
__global__ __launch_bounds__(256) void k_sn_ln(const float* __restrict__ parts,
        const float* __restrict__ bcp, const float* __restrict__ mgb,
        const float* __restrict__ sg, const float* __restrict__ sb,
        float* __restrict__ h,
        const float* __restrict__ n2g, const float* __restrict__ n2b,
        u16* __restrict__ hn2){
    int row = blockIdx.x*4 + (threadIdx.x>>6);
    int lane = threadIdx.x & 63;
    float v[6]; float s = 0.f;
    #pragma unroll
    for (int i=0;i<6;i++){
        int c = lane + i*64;
        long long o = (long long)row*384 + c;
        float t = mgb[c] + bcp[c] + bcp[384+c] + bcp[768+c] + bcp[1152+c];
        #pragma unroll
        for (int p=0;p<8;p++) t += parts[(long long)p*MP*384 + o];
        v[i] = t; s += t;
    }
    float mu = wsum(s)*(1.f/384.f);
    float q = 0.f;
    #pragma unroll
    for (int i=0;i<6;i++){ float d = v[i]-mu; q += d*d; }
    float rs = rsqrtf(wsum(q)*(1.f/384.f) + 1e-5f);
    float* hp = h + (long long)row*384;
    float hv[6]; float s2 = 0.f;
    #pragma unroll
    for (int i=0;i<6;i++){
        int c = lane + i*64;
        float nv = hp[c] + (v[i]-mu)*rs*sg[c] + sb[c];
        hp[c] = nv; hv[i] = nv; s2 += nv;
    }
    float mu2 = wsum(s2)*(1.f/384.f);
    float q2 = 0.f;
    #pragma unroll
    for (int i=0;i<6;i++){ float d = hv[i]-mu2; q2 += d*d; }
    float rs2 = rsqrtf(wsum(q2)*(1.f/384.f) + 1e-5f);
    u16* op = hn2 + (long long)row*384;
    #pragma unroll
    for (int i=0;i<6;i++){ int c = lane + i*64; op[c] = f2b((hv[i]-mu2)*rs2*n2g[c] + n2b[c]); }
}

// gated SiLU*sigmoid + per-768 LN
__global__ __launch_bounds__(256) void k_gate_ln(const u16* __restrict__ zg,
        const float* __restrict__ lag, const float* __restrict__ lab, u16* __restrict__ lnz){
    int unit = blockIdx.x*4 + (threadIdx.x>>6);
    int lane = threadIdx.x & 63;
    int row = unit >> 2, dir = unit & 3;
    const u16* zp = zg + (long long)row*6144 + dir*1536;
    float gated[12]; float s = 0.f;
    #pragma unroll
    for (int p=0;p<3;p++){
        int j = p*256 + lane*4;
        ushort4 zv = *reinterpret_cast<const ushort4*>(zp + j);
        ushort4 gv = *reinterpret_cast<const ushort4*>(zp + 768 + j);
        const u16* za = (const u16*)&zv;
        const u16* ga = (const u16*)&gv;
        #pragma unroll
        for (int qq=0;qq<4;qq++){
            float zf = b2f(za[qq]);
            float gf = b2f(ga[qq]);
            float val = zf/(1.f+__expf(-zf)) * (1.f/(1.f+__expf(-gf)));
            gated[p*4+qq] = val; s += val;
        }
    }
    float mu = wsum(s)*(1.f/768.f);
    float q = 0.f;
    #pragma unroll
    for (int i=0;i<12;i++){ float d = gated[i]-mu; q += d*d; }
    float rs = rsqrtf(wsum(q)*(1.f/768.f) + 1e-5f);
    const float* gg = lag + dir*768;
    const float* bb = lab + dir*768;
    u16* op = lnz + (long long)row*3072 + dir*768;
    #pragma unroll
    for (int p=0;p<3;p++){
        int j = p*256 + lane*4;
        ushort4 ov;
        u16* oa = (u16*)&ov;
        #pragma unroll
        for (int qq=0;qq<4;qq++)
            oa[qq] = f2b((gated[p*4+qq]-mu)*rs*gg[j+qq] + bb[j+qq]);
        *reinterpret_cast<ushort4*>(op + j) = ov;
    }
}

// --------------------------------------------------------------------------
extern "C" void kernel_launch(void* const* d_in, const int* in_sizes, int n_in,
                              void* d_out, int out_size, void* d_ws, size_t ws_size,
                              hipStream_t stream)
{
    const float* x      = (const float*)d_in[0];
    const float* patch_w= (const float*)d_in[1];
    const float* patch_b= (const float*)d_in[2];
    const float* pe_g   = (const float*)d_in[3];
    const float* pe_b   = (const float*)d_in[4];
    const float* pos    = (const float*)d_in[5];
    const float* n1_g   = (const float*)d_in[6];
    const float* n1_b   = (const float*)d_in[7];
    const float* pi_w   = (const float*)d_in[8];
    const float* pi_b   = (const float*)d_in[9];
    const float* po_w   = (const float*)d_in[10];
    const float* po_b   = (const float*)d_in[11];
    const float* la_g   = (const float*)d_in[12];
    const float* la_b   = (const float*)d_in[13];
    const float* mg_w   = (const float*)d_in[14];
    const float* mg_b   = (const float*)d_in[15];
    const float* sn_g   = (const float*)d_in[16];
    const float* sn_b   = (const float*)d_in[17];
    const float* n2_g   = (const float*)d_in[18];
    const float* n2_b   = (const float*)d_in[19];
    const float* m1_w   = (const float*)d_in[20];
    const float* m1_b   = (const float*)d_in[21];
    const float* m2_w   = (const float*)d_in[22];
    const float* m2_b   = (const float*)d_in[23];
    const float* fin_g  = (const float*)d_in[24];
    const float* fin_b  = (const float*)d_in[25];

    char* wptr = (char*)d_ws;
    auto carve = [&](long long elems, int esz)->void*{
        void* p = (void*)wptr;
        wptr += ((elems*(long long)esz + 255)/256)*256;
        return p;
    };

    u16* wt_pi  = (u16*)carve(28311552, 2);
    u16* wt_mgr = (u16*)carve(7077888, 2);
    u16* wt_m1  = (u16*)carve(7077888, 2);
    u16* wt_m2  = (u16*)carve(7077888, 2);
    u16* wt_pe  = (u16*)carve(294912, 2);
    u16* po_bf  = (u16*)carve(14155776, 2);
    u16* WcT    = (u16*)carve(14155776, 2);
    float* bcp  = (float*)carve(48*384, 4);
    float* h    = (float*)carve((long long)MP*384, 4);
    float* parts= (float*)carve(8LL*MP*384, 4);
    u16* patches= (u16*)carve((long long)MP*768, 2);
    u16* hn     = (u16*)carve((long long)MP*384, 2);
    u16* zg     = (u16*)carve((long long)MP*6144, 2);
    u16* lnz    = (u16*)carve((long long)MP*3072, 2);
    u16* outs   = (u16*)carve((long long)MP*1536, 2);

    dim3 blk(256);

    // ---- one-time weight prep ----
    k_transpose<<<dim3(48,12,48), blk, 0, stream>>>(pi_w,   wt_pi, 384, 1536);
    k_transpose<<<dim3(12,12,48), blk, 0, stream>>>(mg_w,   wt_mgr, 384, 384);
    k_transpose<<<dim3(48,12,12), blk, 0, stream>>>(m1_w,   wt_m1, 384, 1536);
    k_transpose<<<dim3(12,48,12), blk, 0, stream>>>(m2_w,   wt_m2, 1536, 384);
    k_transpose<<<dim3(12,24,1),  blk, 0, stream>>>(patch_w,wt_pe, 768, 384);
    k_cvt<<<dim3(13824), blk, 0, stream>>>((const float4*)po_w, (ushort4*)po_bf, 3538944);
    k_bc<<<dim3(48), dim3(384), 0, stream>>>(po_b, mg_w, bcp);
    gemm_tn<0><<<dim3(6,3,48), blk, 0, stream>>>(
        wt_mgr, 384, 589824LL, 147456LL,
        po_bf,  384, 1179648LL, 294912LL,
        nullptr, 0, 0,
        WcT, 3072, 1179648LL, 768LL, 384, 2);

    // ---- patch embed ----
    k_patches<<<dim3(MP*768/256), blk, 0, stream>>>(x, patches);
    gemm_tn<2><<<dim3(3,25,2), blk, 0, stream>>>(
        patches, 768, 0, 384,
        wt_pe,   768, 0, 384,
        patch_b, 0, 1,
        parts, 384, 0, (long long)MP*384, 384, 1);
    k_pe_ln<<<dim3(MP/4), blk, 0, stream>>>(parts, pe_g, pe_b, pos, h, n1_g, n1_b, hn);

    for (int l=0; l<L_; ++l){
        gemm_tn<0><<<dim3(48,25,1), blk, 0, stream>>>(
            hn, 384, 0, 0,
            wt_pi + (long long)l*2359296, 384, 0, 0,
            pi_b + (long long)l*6144, 0, 0,
            zg, 6144, 0, 0, 384, 0);
        k_gate_ln<<<dim3(MP), blk, 0, stream>>>(zg, la_g + (long long)l*3072, la_b + (long long)l*3072, lnz);
        gemm_tn<2><<<dim3(3,25,8), blk, 0, stream>>>(
            lnz, 3072, 0, 384,
            WcT + (long long)l*1179648, 3072, 0, 384,
            nullptr, 0, 0,
            parts, 384, 0, (long long)MP*384, 384, 3);
        k_sn_ln<<<dim3(MP/4), blk, 0, stream>>>(parts, bcp + (long long)l*1536, mg_b + l*384,
                                                sn_g + l*384, sn_b + l*384,
                                                h, n2_g + l*384, n2_b + l*384, hn);
        gemm_tn<1><<<dim3(12,25,1), blk, 0, stream>>>(
            hn, 384, 0, 0,
            wt_m1 + (long long)l*589824, 384, 0, 0,
            m1_b + (long long)l*1536, 0, 0,
            outs, 1536, 0, 0, 384, 0);
        gemm_tn<2><<<dim3(3,25,4), blk, 0, stream>>>(
            outs, 1536, 0, 384,
            wt_m2 + (long long)l*589824, 1536, 0, 384,
            m2_b + l*384, 0, 1,
            parts, 384, 0, (long long)MP*384, 384, 2);
        if (l < L_-1)
            k_addln<0><<<dim3(MP/4), blk, 0, stream>>>(h, parts, 4,
                n1_g + (l+1)*384, n1_b + (l+1)*384, hn);
        else
            k_addln<1><<<dim3(NTOK/4), blk, 0, stream>>>(h, parts, 4,
                fin_g, fin_b, (float*)d_out);
    }
}

// Round 5
// 1648.593 us; speedup vs baseline: 1.3245x; 1.0317x over previous
//
#include <hip/hip_runtime.h>
#include <math.h>

typedef unsigned short u16;
typedef __bf16 bf16x8 __attribute__((ext_vector_type(8)));
typedef float f32x4 __attribute__((ext_vector_type(4)));

#define L_   12
#define NTOK 3136
#define MP   3200

__device__ __forceinline__ float b2f(u16 v){ return __builtin_bit_cast(float, (unsigned)v<<16); }
__device__ __forceinline__ u16 f2b(float f){
    unsigned u = __builtin_bit_cast(unsigned, f);
    u += 0x7fffu + ((u>>16)&1u);
    return (u16)(u>>16);
}
__device__ __forceinline__ float wsum(float v){
    #pragma unroll
    for (int o=32;o;o>>=1) v += __shfl_xor(v,o);
    return v;
}
__device__ __forceinline__ void gl_lds16(const void* g, void* l){
    __builtin_amdgcn_global_load_lds(
        (const __attribute__((address_space(1))) void*)g,
        (__attribute__((address_space(3))) void*)l, 16, 0, 0);
}

// ---------------- weight transpose + fp32->bf16 convert -------------------
__global__ __launch_bounds__(256) void k_transpose(const float* __restrict__ src,
                                                   u16* __restrict__ dst, int R, int C){
    __shared__ float t[32][33];
    long long base = (long long)blockIdx.z * R * C;
    int c0 = blockIdx.x<<5, r0 = blockIdx.y<<5;
    int tx = threadIdx.x & 31, ty = threadIdx.x >> 5;
    #pragma unroll
    for (int i=0;i<32;i+=8)
        t[ty+i][tx] = src[base + (long long)(r0+ty+i)*C + c0 + tx];
    __syncthreads();
    #pragma unroll
    for (int i=0;i<32;i+=8)
        dst[base + (long long)(c0+ty+i)*R + r0 + tx] = f2b(t[tx][ty+i]);
}

// pi transpose with z/gate column interleave: dst row rho(c), rho(c)=2c (c<768), 2(c-768)+1
__global__ __launch_bounds__(256) void k_transpose_pi(const float* __restrict__ src,
                                                      u16* __restrict__ dst){
    const int R = 384, C = 1536;
    __shared__ float t[32][33];
    long long base = (long long)blockIdx.z * R * C;
    int c0 = blockIdx.x<<5, r0 = blockIdx.y<<5;
    int tx = threadIdx.x & 31, ty = threadIdx.x >> 5;
    #pragma unroll
    for (int i=0;i<32;i+=8)
        t[ty+i][tx] = src[base + (long long)(r0+ty+i)*C + c0 + tx];
    __syncthreads();
    #pragma unroll
    for (int i=0;i<32;i+=8){
        int c = c0 + ty + i;
        int rho = (c < 768) ? (c<<1) : (((c-768)<<1)|1);
        dst[base + (long long)rho*R + r0 + tx] = f2b(t[tx][ty+i]);
    }
}

// interleaved pi bias: pib_i[l][dir*1536 + rho(c)] = pi_b[l,dir,c]
__global__ __launch_bounds__(256) void k_bi(const float* __restrict__ pi_b, float* __restrict__ out){
    int idx = blockIdx.x*256 + threadIdx.x;     // 48*1536
    if (idx >= 48*1536) return;
    int slab = idx / 1536, c = idx - slab*1536;
    int l = slab >> 2, dir = slab & 3;
    int rho = (c < 768) ? (c<<1) : (((c-768)<<1)|1);
    out[(long long)l*6144 + dir*1536 + rho] = pi_b[idx];
}

// plain fp32 -> bf16 convert
__global__ __launch_bounds__(256) void k_cvt(const float4* __restrict__ src,
                                             ushort4* __restrict__ dst, int n4){
    int i = blockIdx.x*256 + threadIdx.x;
    if (i < n4){
        float4 v = src[i];
        ushort4 o; o.x=f2b(v.x); o.y=f2b(v.y); o.z=f2b(v.z); o.w=f2b(v.w);
        dst[i] = o;
    }
}

// bias fold for fused po+mg
__global__ __launch_bounds__(384) void k_bc(const float* __restrict__ po_b,
                                            const float* __restrict__ mg_w,
                                            float* __restrict__ bcp){
    int z = blockIdx.x;
    int i = threadIdx.x;
    const float* pb = po_b + (long long)z*384;
    const float* mw = mg_w + (long long)z*384*384;
    float s = 0.f;
    for (int k=0;k<384;k++) s = fmaf(pb[k], mw[(long long)k*384 + i], s);
    bcp[(long long)z*384 + i] = s;
}

// ---------------- patch extraction ---------------------------------------
__global__ __launch_bounds__(256) void k_patches(const float* __restrict__ x, u16* __restrict__ out){
    int idx = blockIdx.x*256 + threadIdx.x;
    int row = idx / 768, col = idx - row*768;
    float v = 0.f;
    if (row < NTOK){
        int b = row / 196, t = row - b*196;
        int gi = t / 14, gj = t - gi*14;
        int c = col >> 8, rem = col & 255, pi = rem >> 4, pj = rem & 15;
        v = x[((long long)(b*3 + c)*224 + gi*16 + pi)*224 + gj*16 + pj];
    }
    out[idx] = f2b(v);
}

// ---------------- GEMM: C = A(M,K)bf16 @ Bt(N,K)bf16 (+bias) --------------
// BM in {128,64}; BN=128. Counted-vmcnt double-buffered pipeline (even nkt).
// EPI: 0 bf16, 1 bf16+GELU, 2 f32, 3 gated-silu-sigmoid bf16 (interleaved cols)
template<int EPI, int BM>
__global__ __launch_bounds__(256) void gemm_tn(
    const u16* __restrict__ A, int lda, long long aSh, long long aSl,
    const u16* __restrict__ Bt, int ldb, long long bSh, long long bSl,
    const float* __restrict__ bias, long long biasSh, int splitBias,
    void* __restrict__ Cbase, int ldc, long long cSh, long long cSl,
    int K, int zshift)
{
    constexpr int NF = (BM==128) ? 4 : 2;   // B frags per wave
    constexpr int AI = (BM==128) ? 4 : 2;   // A stage issues per thread
    int z = blockIdx.z;
    int zh = z >> zshift, zl = z - (zh << zshift);
    const u16* Az  = A  + zh*aSh + zl*aSl;
    const u16* Btz = Bt + zh*bSh + zl*bSl;
    bool addb = bias && (!splitBias || zl == 0);
    long long cOff = zh*cSh + zl*cSl;
    int m0 = blockIdx.y*BM, n0 = blockIdx.x*128;

    __shared__ u16 As[2][BM*64];
    __shared__ u16 Bs[2][8192];

    int tid = threadIdx.x;
    int lane = tid & 63;
    int w = tid >> 6;
    int wrb = (BM==128) ? (w>>1)*64 : 0;
    int wcb = (BM==128) ? (w&1)*64 : w*32;
    int rsub = lane >> 3, csub = lane & 7;
    int scol = ((csub ^ rsub) << 3);     // swizzled source column (elements)
    int kxor = (lane & 7) << 4;

    const u16* ga[AI]; const u16* gb[4]; int loa[AI], lob[4];
    #pragma unroll
    for (int j=0;j<AI;j++){
        int r = j*32 + w*8 + rsub;
        ga[j] = Az + (long long)(m0 + r)*lda + scol;
        loa[j] = (j*32 + w*8)*64;
    }
    #pragma unroll
    for (int j=0;j<4;j++){
        int r = j*32 + w*8 + rsub;
        gb[j] = Btz + (long long)(n0 + r)*ldb + scol;
        lob[j] = (j*32 + w*8)*64;
    }

    f32x4 acc[4][NF];
    #pragma unroll
    for (int m=0;m<4;m++)
        #pragma unroll
        for (int n=0;n<NF;n++) acc[m][n] = (f32x4){0.f,0.f,0.f,0.f};

    int nkt = K >> 6;   // must be even

    auto stage = [&](int ko, int p){
        #pragma unroll
        for (int j=0;j<AI;j++) gl_lds16(ga[j] + ko, &As[p][loa[j]]);
        #pragma unroll
        for (int j=0;j<4;j++)  gl_lds16(gb[j] + ko, &Bs[p][lob[j]]);
    };

    stage(0, 0);
    stage(64, 1);

    auto step = [&](int kt, int p){
        if (kt == nkt-1)               asm volatile("s_waitcnt vmcnt(0)" ::: "memory");
        else if constexpr (BM==128)    asm volatile("s_waitcnt vmcnt(8)" ::: "memory");
        else                           asm volatile("s_waitcnt vmcnt(6)" ::: "memory");
        __builtin_amdgcn_s_barrier();
        const char* as = (const char*)As[p];
        const char* bs = (const char*)Bs[p];
        bf16x8 af[2][4], bfr[2][NF];
        #pragma unroll
        for (int kk=0; kk<2; ++kk){
            int kb = ((kk*32 + ((lane>>4)<<3))*2) ^ kxor;
            #pragma unroll
            for (int m=0;m<4;m++){
                int r = wrb + m*16 + (lane&15);
                af[kk][m] = *reinterpret_cast<const bf16x8*>(as + r*128 + kb);
            }
            #pragma unroll
            for (int n=0;n<NF;n++){
                int r = wcb + n*16 + (lane&15);
                bfr[kk][n] = *reinterpret_cast<const bf16x8*>(bs + r*128 + kb);
            }
        }
        asm volatile("s_waitcnt lgkmcnt(0)" ::: "memory");
        __builtin_amdgcn_sched_barrier(0);
        __builtin_amdgcn_s_barrier();   // all waves done reading buf[p]
        if (kt+2 < nkt) stage((kt+2)<<6, p);
        #pragma unroll
        for (int kk=0; kk<2; ++kk)
            #pragma unroll
            for (int m=0;m<4;m++)
                #pragma unroll
                for (int n=0;n<NF;n++)
                    acc[m][n] = __builtin_amdgcn_mfma_f32_16x16x32_bf16(af[kk][m], bfr[kk][n], acc[m][n], 0,0,0);
    };

    for (int kt=0; kt<nkt; kt+=2){ step(kt, 0); step(kt+1, 1); }

    int rbase = m0 + wrb;
    int nbase = n0 + wcb;
    #pragma unroll
    for (int m=0;m<4;m++){
        #pragma unroll
        for (int n=0;n<NF;n++){
            int ncol = nbase + n*16 + (lane&15);
            float bv = addb ? bias[zh*biasSh + ncol] : 0.f;
            if (EPI==3){
                int dir = ncol/1536, ci = ncol - dir*1536;
                #pragma unroll
                for (int r4=0;r4<4;r4++){
                    float v = acc[m][n][r4] + bv;
                    float pp = __shfl_xor(v, 1);
                    float zf = (lane&1) ? pp : v;
                    float gf = (lane&1) ? v : pp;
                    float gv = zf/(1.f+__expf(-zf)) * (1.f/(1.f+__expf(-gf)));
                    if (!(lane&1)){
                        int row = rbase + m*16 + ((lane>>4)<<2) + r4;
                        ((u16*)Cbase)[(long long)row*3072 + dir*768 + (ci>>1)] = f2b(gv);
                    }
                }
            } else {
                #pragma unroll
                for (int r4=0;r4<4;r4++){
                    int row = rbase + m*16 + ((lane>>4)<<2) + r4;
                    float v = acc[m][n][r4] + bv;
                    long long idx = (long long)row*ldc + ncol + cOff;
                    if (EPI==0)      ((u16*)Cbase)[idx] = f2b(v);
                    else if (EPI==1){
                        float gl = 0.5f*v*(1.f + erff(v*0.70710678118f));
                        ((u16*)Cbase)[idx] = f2b(gl);
                    }
                    else             ((float*)Cbase)[idx] = v;
                }
            }
        }
    }
}

// -------- h += sum(parts[np]); LN -> out. MODE 0: bf16 out + update h. MODE 1: f32 out.
template<int MODE>
__global__ __launch_bounds__(256) void k_addln(float* __restrict__ h,
        const float* __restrict__ parts, int np,
        const float* __restrict__ g, const float* __restrict__ b, void* __restrict__ out){
    int row = blockIdx.x*4 + (threadIdx.x>>6);
    int lane = threadIdx.x & 63;
    float* hp = h + (long long)row*384;
    float v[6]; float s = 0.f;
    #pragma unroll
    for (int i=0;i<6;i++){
        int c = lane + i*64;
        float t = hp[c];
        for (int p=0;p<np;p++) t += parts[(long long)p*MP*384 + (long long)row*384 + c];
        v[i] = t; s += t;
    }
    if (MODE==0 && np){
        #pragma unroll
        for (int i=0;i<6;i++) hp[lane + i*64] = v[i];
    }
    float mu = wsum(s)*(1.f/384.f);
    float q = 0.f;
    #pragma unroll
    for (int i=0;i<6;i++){ float d = v[i]-mu; q += d*d; }
    float rs = rsqrtf(wsum(q)*(1.f/384.f) + 1e-5f);
    if (MODE==0){
        u16* op = (u16*)out + (long long)row*384;
        #pragma unroll
        for (int i=0;i<6;i++){ int c = lane + i*64; op[c] = f2b((v[i]-mu)*rs*g[c] + b[c]); }
    } else {
        float* op = (float*)out + (long long)row*384;
        #pragma unroll
        for (int i=0;i<6;i++){ int c = lane + i*64; op[c] = (v[i]-mu)*rs*g[c] + b[c]; }
    }
}

// patch-embed: sum 2 parts -> LN(pe) -> +pos -> h; then LN(n1[0]) -> hn bf16
__global__ __launch_bounds__(256) void k_pe_ln(const float* __restrict__ parts,
        const float* __restrict__ g, const float* __restrict__ b,
        const float* __restrict__ pos, float* __restrict__ h,
        const float* __restrict__ n1g, const float* __restrict__ n1b,
        u16* __restrict__ hn){
    int row = blockIdx.x*4 + (threadIdx.x>>6);
    int lane = threadIdx.x & 63;
    float v[6]; float s = 0.f;
    #pragma unroll
    for (int i=0;i<6;i++){
        int c = lane + i*64;
        float t = parts[(long long)row*384 + c] + parts[(long long)MP*384 + (long long)row*384 + c];
        v[i] = t; s += t;
    }
    float mu = wsum(s)*(1.f/384.f);
    float q = 0.f;
    #pragma unroll
    for (int i=0;i<6;i++){ float d = v[i]-mu; q += d*d; }
    float rs = rsqrtf(wsum(q)*(1.f/384.f) + 1e-5f);
    int t = row % 196;
    const float* pp = pos + (long long)t*384;
    float* op = h + (long long)row*384;
    float hv[6]; float s2 = 0.f;
    #pragma unroll
    for (int i=0;i<6;i++){
        int c = lane + i*64;
        float nv = (v[i]-mu)*rs*g[c] + b[c] + pp[c];
        op[c] = nv; hv[i] = nv; s2 += nv;
    }
    float mu2 = wsum(s2)*(1.f/384.f);
    float q2 = 0.f;
    #pragma unroll
    for (int i=0;i<6;i++){ float d = hv[i]-mu2; q2 += d*d; }
    float rs2 = rsqrtf(wsum(q2)*(1.f/384.f) + 1e-5f);
    u16* hp = hn + (long long)row*384;
    #pragma unroll
    for (int i=0;i<6;i++){ int c = lane + i*64; hp[c] = f2b((hv[i]-mu2)*rs2*n1g[c] + n1b[c]); }
}

// sum 4 parts + bias terms -> LN(sn) -> h += -> LN(n2) -> hn bf16
__global__ __launch_bounds__(256) void k_sn_ln(const float* __restrict__ parts,
        const float* __restrict__ bcp, const float* __restrict__ mgb,
        const float* __restrict__ sg, const float* __restrict__ sb,
        float* __restrict__ h,
        const float* __restrict__ n2g, const float* __restrict__ n2b,
        u16* __restrict__ hn2){
    int row = blockIdx.x*4 + (threadIdx.x>>6);
    int lane = threadIdx.x & 63;
    float v[6]; float s = 0.f;
    #pragma unroll
    for (int i=0;i<6;i++){
        int c = lane + i*64;
        long long o = (long long)row*384 + c;
        float t = mgb[c] + bcp[c] + bcp[384+c] + bcp[768+c] + bcp[1152+c];
        #pragma unroll
        for (int p=0;p<4;p++) t += parts[(long long)p*MP*384 + o];
        v[i] = t; s += t;
    }
    float mu = wsum(s)*(1.f/384.f);
    float q = 0.f;
    #pragma unroll
    for (int i=0;i<6;i++){ float d = v[i]-mu; q += d*d; }
    float rs = rsqrtf(wsum(q)*(1.f/384.f) + 1e-5f);
    float* hp = h + (long long)row*384;
    float hv[6]; float s2 = 0.f;
    #pragma unroll
    for (int i=0;i<6;i++){
        int c = lane + i*64;
        float nv = hp[c] + (v[i]-mu)*rs*sg[c] + sb[c];
        hp[c] = nv; hv[i] = nv; s2 += nv;
    }
    float mu2 = wsum(s2)*(1.f/384.f);
    float q2 = 0.f;
    #pragma unroll
    for (int i=0;i<6;i++){ float d = hv[i]-mu2; q2 += d*d; }
    float rs2 = rsqrtf(wsum(q2)*(1.f/384.f) + 1e-5f);
    u16* op = hn2 + (long long)row*384;
    #pragma unroll
    for (int i=0;i<6;i++){ int c = lane + i*64; op[c] = f2b((hv[i]-mu2)*rs2*n2g[c] + n2b[c]); }
}

// per-768 LN on pre-gated values: gated(MP,3072)bf16 -> lnz(MP,3072)bf16
__global__ __launch_bounds__(256) void k_lngate(const u16* __restrict__ gated,
        const float* __restrict__ lag, const float* __restrict__ lab, u16* __restrict__ lnz){
    int unit = blockIdx.x*4 + (threadIdx.x>>6);
    int lane = threadIdx.x & 63;
    int row = unit >> 2, dir = unit & 3;
    const u16* zp = gated + (long long)row*3072 + dir*768;
    float gv[12]; float s = 0.f;
    #pragma unroll
    for (int p=0;p<3;p++){
        int j = p*256 + lane*4;
        ushort4 zv = *reinterpret_cast<const ushort4*>(zp + j);
        const u16* za = (const u16*)&zv;
        #pragma unroll
        for (int qq=0;qq<4;qq++){
            float val = b2f(za[qq]);
            gv[p*4+qq] = val; s += val;
        }
    }
    float mu = wsum(s)*(1.f/768.f);
    float q = 0.f;
    #pragma unroll
    for (int i=0;i<12;i++){ float d = gv[i]-mu; q += d*d; }
    float rs = rsqrtf(wsum(q)*(1.f/768.f) + 1e-5f);
    const float* gg = lag + dir*768;
    const float* bb = lab + dir*768;
    u16* op = lnz + (long long)row*3072 + dir*768;
    #pragma unroll
    for (int p=0;p<3;p++){
        int j = p*256 + lane*4;
        ushort4 ov;
        u16* oa = (u16*)&ov;
        #pragma unroll
        for (int qq=0;qq<4;qq++)
            oa[qq] = f2b((gv[p*4+qq]-mu)*rs*gg[j+qq] + bb[j+qq]);
        *reinterpret_cast<ushort4*>(op + j) = ov;
    }
}

// --------------------------------------------------------------------------
extern "C" void kernel_launch(void* const* d_in, const int* in_sizes, int n_in,
                              void* d_out, int out_size, void* d_ws, size_t ws_size,
                              hipStream_t stream)
{
    const float* x      = (const float*)d_in[0];
    const float* patch_w= (const float*)d_in[1];
    const float* patch_b= (const float*)d_in[2];
    const float* pe_g   = (const float*)d_in[3];
    const float* pe_b   = (const float*)d_in[4];
    const float* pos    = (const float*)d_in[5];
    const float* n1_g   = (const float*)d_in[6];
    const float* n1_b   = (const float*)d_in[7];
    const float* pi_w   = (const float*)d_in[8];
    const float* pi_b   = (const float*)d_in[9];
    const float* po_w   = (const float*)d_in[10];
    const float* po_b   = (const float*)d_in[11];
    const float* la_g   = (const float*)d_in[12];
    const float* la_b   = (const float*)d_in[13];
    const float* mg_w   = (const float*)d_in[14];
    const float* mg_b   = (const float*)d_in[15];
    const float* sn_g   = (const float*)d_in[16];
    const float* sn_b   = (const float*)d_in[17];
    const float* n2_g   = (const float*)d_in[18];
    const float* n2_b   = (const float*)d_in[19];
    const float* m1_w   = (const float*)d_in[20];
    const float* m1_b   = (const float*)d_in[21];
    const float* m2_w   = (const float*)d_in[22];
    const float* m2_b   = (const float*)d_in[23];
    const float* fin_g  = (const float*)d_in[24];
    const float* fin_b  = (const float*)d_in[25];

    char* wptr = (char*)d_ws;
    auto carve = [&](long long elems, int esz)->void*{
        void* p = (void*)wptr;
        wptr += ((elems*(long long)esz + 255)/256)*256;
        return p;
    };

    u16* wt_pi  = (u16*)carve(28311552, 2);   // 48 x (1536,384), z/gate-interleaved rows
    u16* wt_mgr = (u16*)carve(7077888, 2);
    u16* wt_m1  = (u16*)carve(7077888, 2);
    u16* wt_m2  = (u16*)carve(7077888, 2);
    u16* wt_pe  = (u16*)carve(294912, 2);
    u16* po_bf  = (u16*)carve(14155776, 2);
    u16* WcT    = (u16*)carve(14155776, 2);
    float* bcp  = (float*)carve(48*384, 4);
    float* pib_i= (float*)carve(12*6144, 4);
    float* h    = (float*)carve((long long)MP*384, 4);
    float* parts= (float*)carve(4LL*MP*384, 4);
    u16* patches= (u16*)carve((long long)MP*768, 2);
    u16* hn     = (u16*)carve((long long)MP*384, 2);
    u16* gated  = (u16*)carve((long long)MP*3072, 2);
    u16* lnz    = (u16*)carve((long long)MP*3072, 2);
    u16* outs   = (u16*)carve((long long)MP*1536, 2);

    dim3 blk(256);

    // ---- one-time weight prep ----
    k_transpose_pi<<<dim3(48,12,48), blk, 0, stream>>>(pi_w, wt_pi);
    k_bi<<<dim3((48*1536+255)/256), blk, 0, stream>>>(pi_b, pib_i);
    k_transpose<<<dim3(12,12,48), blk, 0, stream>>>(mg_w,   wt_mgr, 384, 384);
    k_transpose<<<dim3(48,12,12), blk, 0, stream>>>(m1_w,   wt_m1, 384, 1536);
    k_transpose<<<dim3(12,48,12), blk, 0, stream>>>(m2_w,   wt_m2, 1536, 384);
    k_transpose<<<dim3(12,24,1),  blk, 0, stream>>>(patch_w,wt_pe, 768, 384);
    k_cvt<<<dim3(13824), blk, 0, stream>>>((const float4*)po_w, (ushort4*)po_bf, 3538944);
    k_bc<<<dim3(48), dim3(384), 0, stream>>>(po_b, mg_w, bcp);
    gemm_tn<0,128><<<dim3(6,3,48), blk, 0, stream>>>(
        wt_mgr, 384, 589824LL, 147456LL,
        po_bf,  384, 1179648LL, 294912LL,
        nullptr, 0, 0,
        WcT, 3072, 1179648LL, 768LL, 384, 2);

    // ---- patch embed (split-K=2, BM=64) ----
    k_patches<<<dim3(MP*768/256), blk, 0, stream>>>(x, patches);
    gemm_tn<2,64><<<dim3(3,50,2), blk, 0, stream>>>(
        patches, 768, 0, 384,
        wt_pe,   768, 0, 384,
        patch_b, 0, 1,
        parts, 384, 0, (long long)MP*384, 384, 1);
    k_pe_ln<<<dim3(MP/4), blk, 0, stream>>>(parts, pe_g, pe_b, pos, h, n1_g, n1_b, hn);

    for (int l=0; l<L_; ++l){
        // input projections with fused gating: hn(MP,384) @ (384,6144 interleaved) -> gated(MP,3072)
        gemm_tn<3,128><<<dim3(48,25,1), blk, 0, stream>>>(
            hn, 384, 0, 0,
            wt_pi + (long long)l*2359296, 384, 0, 0,
            pib_i + (long long)l*6144, 0, 0,
            gated, 3072, 0, 0, 384, 0);
        k_lngate<<<dim3(MP), blk, 0, stream>>>(gated, la_g + (long long)l*3072, la_b + (long long)l*3072, lnz);
        // fused po+mg: lnz(MP,3072) @ Wc(3072,384), split-K=4, BM=64
        gemm_tn<2,64><<<dim3(3,50,4), blk, 0, stream>>>(
            lnz, 3072, 0, 768,
            WcT + (long long)l*1179648, 3072, 0, 768,
            nullptr, 0, 0,
            parts, 384, 0, (long long)MP*384, 768, 2);
        k_sn_ln<<<dim3(MP/4), blk, 0, stream>>>(parts, bcp + (long long)l*1536, mg_b + l*384,
                                                sn_g + l*384, sn_b + l*384,
                                                h, n2_g + l*384, n2_b + l*384, hn);
        // MLP up + GELU (BM=64)
        gemm_tn<1,64><<<dim3(12,50,1), blk, 0, stream>>>(
            hn, 384, 0, 0,
            wt_m1 + (long long)l*589824, 384, 0, 0,
            m1_b + (long long)l*1536, 0, 0,
            outs, 1536, 0, 0, 384, 0);
        // MLP down: split-K=4 (BM=64)
        gemm_tn<2,64><<<dim3(3,50,4), blk, 0, stream>>>(
            outs, 1536, 0, 384,
            wt_m2 + (long long)l*589824, 1536, 0, 384,
            m2_b + l*384, 0, 1,
            parts, 384, 0, (long long)MP*384, 384, 2);
        if (l < L_-1)
            k_addln<0><<<dim3(MP/4), blk, 0, stream>>>(h, parts, 4,
                n1_g + (l+1)*384, n1_b + (l+1)*384, hn);
        else
            k_addln<1><<<dim3(NTOK/4), blk, 0, stream>>>(h, parts, 4,
                fin_g, fin_b, (float*)d_out);
    }
}